// Round 20
// baseline (133.146 us; speedup 1.0000x reference)
//
#include <hip/hip_runtime.h>
#include <math.h>

#define NLOC 32768
#define CH 256

typedef __attribute__((ext_vector_type(8))) short short8;
typedef __attribute__((ext_vector_type(4))) float floatx4;

__device__ inline unsigned short f2bf(float x) {
  union { float f; unsigned u; } c; c.f = x;
  unsigned r = c.u + 0x7FFFu + ((c.u >> 16) & 1u);
  return (unsigned short)(r >> 16);
}
__device__ inline float bflo(unsigned u) {
  union { unsigned u; float f; } c; c.u = u << 16; return c.f;
}
__device__ inline float bfhi(unsigned u) {
  union { unsigned u; float f; } c; c.u = u & 0xFFFF0000u; return c.f;
}
__device__ inline float bf2f(unsigned short u) {
  union { unsigned u; float f; } c; c.u = (unsigned)u << 16; return c.f;
}

// async global->LDS 16B: lds dest is wave-uniform base (+lane*16 by HW)
__device__ __forceinline__ void gl_lds16(const void* g, void* l) {
  __builtin_amdgcn_global_load_lds(
      (const __attribute__((address_space(1))) unsigned int*)g,
      (__attribute__((address_space(3))) unsigned int*)l, 16, 0, 0);
}

// ---------------------------------------------------------------------------
// P0: pack Wv/Wfu/Wa(->96 cols, zero-pad) to bf16 MFMA B-fragment order.
__global__ __launch_bounds__(64) void k_pack_w(
    const float* __restrict__ Wv, const float* __restrict__ Wa,
    const float* __restrict__ Wfu, unsigned short* __restrict__ wp) {
  int fid = blockIdx.x;
  int l = threadIdx.x;
  const float* W; int ldn, nvalid, nf, ks;
  if (fid < 128)      { W = Wv;  ldn = 256; nvalid = 256; nf = fid >> 3; ks = fid & 7; }
  else if (fid < 384) { int f = fid - 128; W = Wfu; ldn = 256; nvalid = 256; nf = f >> 4; ks = f & 15; }
  else                { int f = fid - 384; W = Wa;  ldn = 81;  nvalid = 81;  nf = f >> 3; ks = f & 7; }
  unsigned short* dst = wp + (size_t)fid * 512;
  int c = nf * 16 + (l & 15);
  int k0 = ks * 32 + (l >> 4) * 8;
  unsigned short u[8];
#pragma unroll
  for (int j = 0; j < 8; ++j)
    u[j] = (c < nvalid) ? f2bf(W[(size_t)(k0 + j) * ldn + c]) : (unsigned short)0;
  uint4 pk;
  pk.x = u[0] | ((unsigned)u[1] << 16);
  pk.y = u[2] | ((unsigned)u[3] << 16);
  pk.z = u[4] | ((unsigned)u[5] << 16);
  pk.w = u[6] | ((unsigned)u[7] << 16);
  *(uint4*)(dst + l * 8) = pk;
}

// ---------------------------------------------------------------------------
// Separable maxpool row-pass along beta + bf16 cast of x. One thread per (loc,c4)
__global__ __launch_bounds__(256) void k_pool(
    const float* __restrict__ x, unsigned short* __restrict__ rm3,
    unsigned short* __restrict__ rm5, unsigned short* __restrict__ xb) {
  int tid = threadIdx.x;
  int loc = blockIdx.x * 4 + (tid >> 6);
  int beta = loc & 63;
  int c0 = (tid & 63) * 4;
  const float* base = x + ((size_t)loc - beta) * CH + c0;
  const float NI = -INFINITY;
  float4 r3 = {NI, NI, NI, NI}, r5, xv;
#pragma unroll
  for (int d = -1; d <= 1; ++d) {
    int bb = beta + d;
    if ((unsigned)bb >= 64u) continue;
    float4 f = *(const float4*)(base + (size_t)bb * CH);
    if (d == 0) xv = f;
    r3.x = fmaxf(r3.x, f.x); r3.y = fmaxf(r3.y, f.y);
    r3.z = fmaxf(r3.z, f.z); r3.w = fmaxf(r3.w, f.w);
  }
  r5 = r3;
#pragma unroll
  for (int d = -2; d <= 2; d += 4) {
    int bb = beta + d;
    if ((unsigned)bb >= 64u) continue;
    float4 f = *(const float4*)(base + (size_t)bb * CH);
    r5.x = fmaxf(r5.x, f.x); r5.y = fmaxf(r5.y, f.y);
    r5.z = fmaxf(r5.z, f.z); r5.w = fmaxf(r5.w, f.w);
  }
  size_t o = (size_t)loc * CH + c0;
  uint2 p3, p5, px;
  p3.x = f2bf(r3.x) | ((unsigned)f2bf(r3.y) << 16);
  p3.y = f2bf(r3.z) | ((unsigned)f2bf(r3.w) << 16);
  p5.x = f2bf(r5.x) | ((unsigned)f2bf(r5.y) << 16);
  p5.y = f2bf(r5.z) | ((unsigned)f2bf(r5.w) << 16);
  px.x = f2bf(xv.x) | ((unsigned)f2bf(xv.y) << 16);
  px.y = f2bf(xv.z) | ((unsigned)f2bf(xv.w) << 16);
  *(uint2*)(rm3 + o) = p3;
  *(uint2*)(rm5 + o) = p5;
  *(uint2*)(xb + o) = px;
}

// ---------------------------------------------------------------------------
// v = xb @ Wv + bv -> bf16 [loc][256]. 128x128 tile, BK=64, single-buffer
// frag LDS. 512 threads / 8 waves.
__global__ __launch_bounds__(512) void k_gemm_v(
    const unsigned short* __restrict__ xb, const unsigned short* __restrict__ wvp,
    const float* __restrict__ bv, unsigned short* __restrict__ v) {
  __shared__ unsigned short sA[16 * 512];
  __shared__ unsigned short sB[16 * 512];
  int tid = threadIdx.x, lane = tid & 63, w = tid >> 6;
  int r0 = (blockIdx.x >> 1) * 128;
  int nc0 = (blockIdx.x & 1) * 128;
  int mh = w >> 1, nq = w & 1;
  floatx4 acc[2][4];
#pragma unroll
  for (int mt = 0; mt < 2; ++mt)
#pragma unroll
    for (int nf = 0; nf < 4; ++nf) acc[mt][nf] = (floatx4)(0.f);
  for (int kt = 0; kt < 4; ++kt) {
    int kk = kt * 64;
#pragma unroll
    for (int f = 0; f < 4; ++f) {
      int fg = w * 4 + f;
      if (fg < 16) {
        int mt16 = fg >> 1, ks = fg & 1;
        gl_lds16(xb + (size_t)(r0 + mt16 * 16 + (lane & 15)) * CH + kk + ks * 32 + (lane >> 4) * 8,
                 &sA[fg * 512]);
      } else {
        int g = fg - 16, nf16 = g >> 1, ks = g & 1;
        gl_lds16(wvp + ((size_t)((nc0 >> 4) + nf16) * 8 + kt * 2 + ks) * 512 + lane * 8,
                 &sB[g * 512]);
      }
    }
    __syncthreads();
#pragma unroll
    for (int ks = 0; ks < 2; ++ks) {
      short8 af[2], bf[4];
#pragma unroll
      for (int mt = 0; mt < 2; ++mt)
        af[mt] = *(const short8*)&sA[(((mh * 2 + mt) << 1) + ks) * 512 + lane * 8];
#pragma unroll
      for (int nf = 0; nf < 4; ++nf)
        bf[nf] = *(const short8*)&sB[(((nq * 4 + nf) << 1) + ks) * 512 + lane * 8];
#pragma unroll
      for (int mt = 0; mt < 2; ++mt)
#pragma unroll
        for (int nf = 0; nf < 4; ++nf)
          acc[mt][nf] = __builtin_amdgcn_mfma_f32_16x16x32_bf16(af[mt], bf[nf], acc[mt][nf], 0, 0, 0);
    }
    if (kt < 3) __syncthreads();
  }
#pragma unroll
  for (int nf = 0; nf < 4; ++nf) {
    int c = nc0 + nq * 64 + nf * 16 + (lane & 15);
    float bb = bv[c];
#pragma unroll
    for (int mt = 0; mt < 2; ++mt) {
      int crow = r0 + mh * 32 + mt * 16 + (lane >> 4) * 4;
#pragma unroll
      for (int i = 0; i < 4; ++i)
        v[(size_t)(crow + i) * CH + c] = f2bf(acc[mt][nf][i] + bb);
    }
  }
}

// ---------------------------------------------------------------------------
// logits = xb @ Wa + ba (96 cols, 81 valid) -> softmax9 -> A bf16 [loc][81]
__global__ __launch_bounds__(256) void k_gemm_a(
    const unsigned short* __restrict__ xb, const unsigned short* __restrict__ wap,
    const float* __restrict__ ba, unsigned short* __restrict__ A) {
  __shared__ float lg[64][96];
  int tid = threadIdx.x, lane = tid & 63, w = tid >> 6;
  int mtile = blockIdx.x * 4 + w;
  int r0 = mtile * 16;
  floatx4 acc[6];
#pragma unroll
  for (int i = 0; i < 6; ++i) acc[i] = (floatx4)(0.f);
  const unsigned short* abase = xb + (size_t)(r0 + (lane & 15)) * CH + (lane >> 4) * 8;
  for (int ks = 0; ks < 8; ++ks) {
    short8 af = *(const short8*)(abase + ks * 32);
#pragma unroll
    for (int nf = 0; nf < 6; ++nf) {
      short8 bfr = *(const short8*)(wap + ((size_t)(nf * 8) + ks) * 512 + lane * 8);
      acc[nf] = __builtin_amdgcn_mfma_f32_16x16x32_bf16(af, bfr, acc[nf], 0, 0, 0);
    }
  }
  int lrow = w * 16 + (lane >> 4) * 4;
#pragma unroll
  for (int nf = 0; nf < 6; ++nf) {
    int c = nf * 16 + (lane & 15);
    float bb = (c < 81) ? ba[c] : 0.f;
#pragma unroll
    for (int i = 0; i < 4; ++i)
      lg[lrow + i][c] = acc[nf][i] + bb;
  }
  __syncthreads();
  int loc0 = blockIdx.x * 64;
  for (int it = 0; it < 3; ++it) {
    int idx = tid + it * 256;
    if (idx < 576) {
      int row = idx / 9, g = idx % 9;
      float vals[9];
#pragma unroll
      for (int q = 0; q < 9; ++q) vals[q] = lg[row][g * 9 + q];
      float m = vals[0];
#pragma unroll
      for (int q = 1; q < 9; ++q) m = fmaxf(m, vals[q]);
      float s = 0.f;
#pragma unroll
      for (int q = 0; q < 9; ++q) { vals[q] = __expf(vals[q] - m); s += vals[q]; }
      float inv = 1.f / s;
      unsigned short* o = A + (size_t)(loc0 + row) * 81 + g * 9;
#pragma unroll
      for (int q = 0; q < 9; ++q) o[q] = f2bf(vals[q] * inv);
    }
  }
}

// ---------------------------------------------------------------------------
// attention gather (f32 LDS window: unpack ONCE at staging) + col-max -> cat
// 512 threads: 8 betas x 64 ch-threads (4 ch each). LDS ~62KB -> 2 blocks/CU.
// XCD-swizzled blockIdx.
__global__ __launch_bounds__(512) void k_attn(
    const unsigned short* __restrict__ A, const unsigned short* __restrict__ v,
    const unsigned short* __restrict__ rm3, const unsigned short* __restrict__ rm5,
    unsigned short* __restrict__ cat) {
  __shared__ float vsf[5 * 12 * CH];   // 61440 B f32 window; head doubles as a_s
  __shared__ float w5_s[8][25];        // 800 B
  float* a_sf = vsf;                   // [8][81] f32 (dead after fold)
  int tid = threadIdx.x;
  int bid = (blockIdx.x & 7) * 512 + (blockIdx.x >> 3);
  int loc0 = bid * 8;
  int b = loc0 >> 12, alpha = (loc0 >> 6) & 63, beta0 = loc0 & 63;
  for (int idx = tid; idx < 8 * 81; idx += 512) {
    int li = idx / 81, t = idx - li * 81;
    int ij = t / 9, i = ij / 3, j = ij % 3;
    int lh = beta0 + li + 1 - i;
    int lw = alpha + 1 - j;
    float val = 0.f;
    if ((unsigned)lh < 64u && (unsigned)lw < 64u)
      val = bf2f(A[(size_t)(b * 4096 + lh * 64 + lw) * 81 + t]);
    a_sf[li * 81 + t] = val;
  }
  __syncthreads();
  if (tid < 200) {
    int li = tid / 25, o = tid - li * 25;
    int dh = o / 5 - 2, dw = o % 5 - 2;
    float s = 0.f;
    int jlo = dh < 0 ? -dh : 0, jhi = dh > 0 ? 2 - dh : 2;
    int ilo = dw < 0 ? -dw : 0, ihi = dw > 0 ? 2 - dw : 2;
    for (int j = jlo; j <= jhi; ++j)
      for (int i = ilo; i <= ihi; ++i)
        s += a_sf[li * 81 + (i * 3 + j) * 9 + ((i + dw) * 3 + (j + dh))];
    w5_s[li][o] = s;
  }
  __syncthreads();   // a_s dead; vsf about to be overwritten
  // stage v window [5][12][256] as f32 (unpack bf16 once here)
  const unsigned short* vb = v + (size_t)b * 4096 * CH;
  for (int i = tid; i < 1920; i += 512) {
    int row = i / 384, rem = i - row * 384, col = rem >> 5, ch8 = rem & 31;
    int hv = alpha - 2 + row, wv = beta0 - 2 + col;
    uint4 val = {0u, 0u, 0u, 0u};
    if ((unsigned)hv < 64u && (unsigned)wv < 64u)
      val = *(const uint4*)(vb + (size_t)(hv * 64 + wv) * CH + ch8 * 8);
    float* dst = vsf + (size_t)(row * 12 + col) * CH + ch8 * 8;
    float4 f0, f1;
    f0.x = bflo(val.x); f0.y = bfhi(val.x); f0.z = bflo(val.y); f0.w = bfhi(val.y);
    f1.x = bflo(val.z); f1.y = bfhi(val.z); f1.z = bflo(val.w); f1.w = bfhi(val.w);
    *(float4*)(dst) = f0;
    *(float4*)(dst + 4) = f1;
  }
  __syncthreads();
  int li = tid >> 6, tc = tid & 63, c0 = tc * 4;
  int beta = beta0 + li;
  float m1[4], m2[4];
#pragma unroll
  for (int q = 0; q < 4; ++q) { m1[q] = -INFINITY; m2[q] = -INFINITY; }
#pragma unroll
  for (int da = -2; da <= 2; ++da) {
    int aa = alpha + da;
    if ((unsigned)aa >= 64u) continue;
    size_t ro = (size_t)((b * 64 + aa) * 64 + beta) * CH + c0;
    uint2 p5 = *(const uint2*)(rm5 + ro);
    m2[0] = fmaxf(m2[0], bflo(p5.x)); m2[1] = fmaxf(m2[1], bfhi(p5.x));
    m2[2] = fmaxf(m2[2], bflo(p5.y)); m2[3] = fmaxf(m2[3], bfhi(p5.y));
    if (da >= -1 && da <= 1) {
      uint2 p3 = *(const uint2*)(rm3 + ro);
      m1[0] = fmaxf(m1[0], bflo(p3.x)); m1[1] = fmaxf(m1[1], bfhi(p3.x));
      m1[2] = fmaxf(m1[2], bflo(p3.y)); m1[3] = fmaxf(m1[3], bfhi(p3.y));
    }
  }
  float acc[4] = {0.f, 0.f, 0.f, 0.f};
#pragma unroll
  for (int dh = 0; dh < 5; ++dh) {
#pragma unroll
    for (int dw = 0; dw < 5; ++dw) {
      float wgt = w5_s[li][dh * 5 + dw];
      float4 vv = *(const float4*)(vsf + (size_t)(dh * 12 + li + dw) * CH + c0);
      acc[0] = fmaf(wgt, vv.x, acc[0]);
      acc[1] = fmaf(wgt, vv.y, acc[1]);
      acc[2] = fmaf(wgt, vv.z, acc[2]);
      acc[3] = fmaf(wgt, vv.w, acc[3]);
    }
  }
  unsigned short u1[4], u2[4];
#pragma unroll
  for (int q = 0; q < 4; ++q) {
    float x1v = fmaxf(fmaxf(acc[q], 0.f) + m1[q], 0.f);
    float x2v = fmaxf(x1v + m2[q], 0.f);
    u1[q] = f2bf(x1v);
    u2[q] = f2bf(x2v);
  }
  unsigned short* cp = cat + (size_t)(loc0 + li) * 512 + c0;
  uint2 pk1, pk2;
  pk1.x = u1[0] | ((unsigned)u1[1] << 16); pk1.y = u1[2] | ((unsigned)u1[3] << 16);
  pk2.x = u2[0] | ((unsigned)u2[1] << 16); pk2.y = u2[2] | ((unsigned)u2[3] << 16);
  *(uint2*)(cp) = pk1;
  *(uint2*)(cp + 256) = pk2;
}

// ---------------------------------------------------------------------------
// xfu = relu(cat @ Wfu + bfu); outb = bf16(x + xfu) transposed; BN sums (16-banked).
// 64x256 tile (cat read once), BK=64, single-buffer frag LDS. 512 threads.
__global__ __launch_bounds__(512) void k_fuse(
    const unsigned short* __restrict__ xb, const unsigned short* __restrict__ cat,
    const unsigned short* __restrict__ wfp, const float* __restrict__ bfu,
    unsigned short* __restrict__ outb, float* __restrict__ sums16) {
  __shared__ unsigned short sA[8 * 512];    // 8KB: 64 rows x 64k
  __shared__ unsigned short sB[32 * 512];   // 32KB: 256 cols x 64k
  __shared__ float bsum[512];
  int tid = threadIdx.x, lane = tid & 63, w = tid >> 6;
  for (int i = tid; i < 512; i += 512) bsum[i] = 0.f;
  int r0 = blockIdx.x * 64;
  int mh = w >> 2, nq = w & 3;
  floatx4 acc[2][4];
#pragma unroll
  for (int mt = 0; mt < 2; ++mt)
#pragma unroll
    for (int nf = 0; nf < 4; ++nf) acc[mt][nf] = (floatx4)(0.f);
  for (int kt = 0; kt < 8; ++kt) {
    int kk = kt * 64;
#pragma unroll
    for (int f = 0; f < 5; ++f) {
      int fg = w * 5 + f;
      if (fg < 8) {
        int mt16 = fg >> 1, ks = fg & 1;
        gl_lds16(cat + (size_t)(r0 + mt16 * 16 + (lane & 15)) * 512 + kk + ks * 32 + (lane >> 4) * 8,
                 &sA[fg * 512]);
      } else {
        int g = fg - 8;   // 0..31
        int nf16 = g >> 1, ks = g & 1;
        gl_lds16(wfp + ((size_t)nf16 * 16 + kt * 2 + ks) * 512 + lane * 8,
                 &sB[g * 512]);
      }
    }
    __syncthreads();
#pragma unroll
    for (int ks = 0; ks < 2; ++ks) {
      short8 af[2], bf[4];
#pragma unroll
      for (int mt = 0; mt < 2; ++mt)
        af[mt] = *(const short8*)&sA[(((mh * 2 + mt) << 1) + ks) * 512 + lane * 8];
#pragma unroll
      for (int nf = 0; nf < 4; ++nf)
        bf[nf] = *(const short8*)&sB[(((nq * 4 + nf) << 1) + ks) * 512 + lane * 8];
#pragma unroll
      for (int mt = 0; mt < 2; ++mt)
#pragma unroll
        for (int nf = 0; nf < 4; ++nf)
          acc[mt][nf] = __builtin_amdgcn_mfma_f32_16x16x32_bf16(af[mt], bf[nf], acc[mt][nf], 0, 0, 0);
    }
    if (kt < 7) __syncthreads();
  }
#pragma unroll
  for (int nf = 0; nf < 4; ++nf) {
    int c = nq * 64 + nf * 16 + (lane & 15);
    float bb = bfu[c];
    float s = 0.f, ss = 0.f;
#pragma unroll
    for (int mt = 0; mt < 2; ++mt) {
      int crow = r0 + mh * 32 + mt * 16 + (lane >> 4) * 4;
#pragma unroll
      for (int i = 0; i < 4; ++i) {
        int r = crow + i;
        float xv = bf2f(xb[(size_t)r * CH + c]);
        float o = xv + fmaxf(acc[mt][nf][i] + bb, 0.f);
        int b_ = r >> 12, al = (r >> 6) & 63, be = r & 63;
        outb[((size_t)(b_ * 64 + be) * 64 + al) * CH + c] = f2bf(o);
        s += o; ss += o * o;
      }
    }
    s += __shfl_xor(s, 16);  s += __shfl_xor(s, 32);
    ss += __shfl_xor(ss, 16); ss += __shfl_xor(ss, 32);
    if (lane < 16) {
      atomicAdd(&bsum[c], s);
      atomicAdd(&bsum[256 + c], ss);
    }
  }
  __syncthreads();
  float* bank = sums16 + (size_t)(blockIdx.x & 15) * 512;
  for (int i = tid; i < 512; i += 512) atomicAdd(&bank[i], bsum[i]);
}

// ---------------------------------------------------------------------------
__global__ void k_bnprep(const float* __restrict__ sums16,
                         const float* __restrict__ gamma,
                         const float* __restrict__ beta_,
                         float* __restrict__ sc) {
  int c = threadIdx.x;
  float s = 0.f, ss = 0.f;
#pragma unroll
  for (int bk = 0; bk < 16; ++bk) {
    s += sums16[(size_t)bk * 512 + c];
    ss += sums16[(size_t)bk * 512 + 256 + c];
  }
  const float inv_n = 1.f / (float)NLOC;
  float mean = s * inv_n;
  float var = ss * inv_n - mean * mean;
  float scale = gamma[c] * rsqrtf(var + 1e-5f);
  sc[c] = scale;
  sc[256 + c] = beta_[c] - mean * scale;
}

// ---------------------------------------------------------------------------
__global__ __launch_bounds__(256) void k_bn(
    const unsigned short* __restrict__ outb, float* __restrict__ outp,
    const float* __restrict__ sc, int n8) {
  __shared__ float s[512];
  const int tid = threadIdx.x;
  for (int i = tid; i < 512; i += 256) s[i] = sc[i];
  __syncthreads();
  for (int i = blockIdx.x * 256 + tid; i < n8; i += gridDim.x * 256) {
    uint4 pk = ((const uint4*)outb)[i];
    int c0 = (i & 31) * 8;
    float4 o0, o1;
    o0.x = bflo(pk.x) * s[c0 + 0] + s[256 + c0 + 0];
    o0.y = bfhi(pk.x) * s[c0 + 1] + s[256 + c0 + 1];
    o0.z = bflo(pk.y) * s[c0 + 2] + s[256 + c0 + 2];
    o0.w = bfhi(pk.y) * s[c0 + 3] + s[256 + c0 + 3];
    o1.x = bflo(pk.z) * s[c0 + 4] + s[256 + c0 + 4];
    o1.y = bfhi(pk.z) * s[c0 + 5] + s[256 + c0 + 5];
    o1.z = bflo(pk.w) * s[c0 + 6] + s[256 + c0 + 6];
    o1.w = bfhi(pk.w) * s[c0 + 7] + s[256 + c0 + 7];
    ((float4*)outp)[i * 2] = o0;
    ((float4*)outp)[i * 2 + 1] = o1;
  }
}

// ---------------------------------------------------------------------------
extern "C" void kernel_launch(void* const* d_in, const int* in_sizes, int n_in,
                              void* d_out, int out_size, void* d_ws, size_t ws_size,
                              hipStream_t stream) {
  const float* x     = (const float*)d_in[0];
  const float* Wv    = (const float*)d_in[1];
  const float* bv    = (const float*)d_in[2];
  const float* Wa    = (const float*)d_in[3];
  const float* ba    = (const float*)d_in[4];
  const float* Wfu   = (const float*)d_in[5];
  const float* bfu   = (const float*)d_in[6];
  const float* gamma = (const float*)d_in[7];
  const float* beta_ = (const float*)d_in[8];
  float* out = (float*)d_out;

  float* sums16 = (float*)d_ws;                             // 16*512 f32
  float* sc     = sums16 + 16 * 512;                        // 512 f32
  unsigned short* wp   = (unsigned short*)(sc + 512);       // 432*512 bf16
  unsigned short* wvp  = wp;
  unsigned short* wfp  = wp + (size_t)128 * 512;
  unsigned short* wap  = wp + (size_t)384 * 512;
  unsigned short* vbuf = wp + (size_t)432 * 512;            // NLOC*256 bf16 (v; reused as outb)
  unsigned short* Abuf = vbuf + (size_t)NLOC * CH;          // NLOC*81 bf16
  unsigned short* cat  = Abuf + (size_t)NLOC * 81;          // NLOC*512 bf16
  unsigned short* rm3  = cat + (size_t)NLOC * 512;          // NLOC*256 bf16
  unsigned short* rm5  = rm3 + (size_t)NLOC * CH;           // NLOC*256 bf16
  unsigned short* xb   = rm5 + (size_t)NLOC * CH;           // NLOC*256 bf16
  unsigned short* outb = vbuf;  // v dead after k_attn -> reuse for pre-BN out

  hipMemsetAsync(sums16, 0, 16 * 512 * sizeof(float), stream);

  k_pack_w<<<432, 64, 0, stream>>>(Wv, Wa, Wfu, wp);
  k_pool<<<8192, 256, 0, stream>>>(x, rm3, rm5, xb);
  k_gemm_v<<<512, 512, 0, stream>>>(xb, wvp, bv, vbuf);
  k_gemm_a<<<512, 256, 0, stream>>>(xb, wap, ba, Abuf);
  k_attn<<<4096, 512, 0, stream>>>(Abuf, vbuf, rm3, rm5, cat);
  k_fuse<<<512, 512, 0, stream>>>(xb, cat, wfp, bfu, outb, sums16);
  k_bnprep<<<1, 256, 0, stream>>>(sums16, gamma, beta_, sc);
  k_bn<<<2048, 256, 0, stream>>>(outb, out, sc, NLOC * CH / 8);
}

// Round 21
// 118.781 us; speedup vs baseline: 1.1209x; 1.1209x over previous
//
#include <hip/hip_runtime.h>
#include <math.h>

#define NLOC 32768
#define CH 256

typedef __attribute__((ext_vector_type(8))) short short8;
typedef __attribute__((ext_vector_type(4))) float floatx4;

__device__ inline unsigned short f2bf(float x) {
  union { float f; unsigned u; } c; c.f = x;
  unsigned r = c.u + 0x7FFFu + ((c.u >> 16) & 1u);
  return (unsigned short)(r >> 16);
}
__device__ inline float bflo(unsigned u) {
  union { unsigned u; float f; } c; c.u = u << 16; return c.f;
}
__device__ inline float bfhi(unsigned u) {
  union { unsigned u; float f; } c; c.u = u & 0xFFFF0000u; return c.f;
}
__device__ inline float bf2f(unsigned short u) {
  union { unsigned u; float f; } c; c.u = (unsigned)u << 16; return c.f;
}

// async global->LDS 16B: lds dest is wave-uniform base (+lane*16 by HW)
__device__ __forceinline__ void gl_lds16(const void* g, void* l) {
  __builtin_amdgcn_global_load_lds(
      (const __attribute__((address_space(1))) unsigned int*)g,
      (__attribute__((address_space(3))) unsigned int*)l, 16, 0, 0);
}

// ---------------------------------------------------------------------------
// P0: pack Wv/Wfu/Wa(->96 cols, zero-pad) to bf16 MFMA B-fragment order.
__global__ __launch_bounds__(64) void k_pack_w(
    const float* __restrict__ Wv, const float* __restrict__ Wa,
    const float* __restrict__ Wfu, unsigned short* __restrict__ wp) {
  int fid = blockIdx.x;
  int l = threadIdx.x;
  const float* W; int ldn, nvalid, nf, ks;
  if (fid < 128)      { W = Wv;  ldn = 256; nvalid = 256; nf = fid >> 3; ks = fid & 7; }
  else if (fid < 384) { int f = fid - 128; W = Wfu; ldn = 256; nvalid = 256; nf = f >> 4; ks = f & 15; }
  else                { int f = fid - 384; W = Wa;  ldn = 81;  nvalid = 81;  nf = f >> 3; ks = f & 7; }
  unsigned short* dst = wp + (size_t)fid * 512;
  int c = nf * 16 + (l & 15);
  int k0 = ks * 32 + (l >> 4) * 8;
  unsigned short u[8];
#pragma unroll
  for (int j = 0; j < 8; ++j)
    u[j] = (c < nvalid) ? f2bf(W[(size_t)(k0 + j) * ldn + c]) : (unsigned short)0;
  uint4 pk;
  pk.x = u[0] | ((unsigned)u[1] << 16);
  pk.y = u[2] | ((unsigned)u[3] << 16);
  pk.z = u[4] | ((unsigned)u[5] << 16);
  pk.w = u[6] | ((unsigned)u[7] << 16);
  *(uint4*)(dst + l * 8) = pk;
}

// ---------------------------------------------------------------------------
// Separable maxpool row-pass along beta + bf16 cast of x. One thread per (loc,c4)
__global__ __launch_bounds__(256) void k_pool(
    const float* __restrict__ x, unsigned short* __restrict__ rm3,
    unsigned short* __restrict__ rm5, unsigned short* __restrict__ xb) {
  int tid = threadIdx.x;
  int loc = blockIdx.x * 4 + (tid >> 6);
  int beta = loc & 63;
  int c0 = (tid & 63) * 4;
  const float* base = x + ((size_t)loc - beta) * CH + c0;
  const float NI = -INFINITY;
  float4 r3 = {NI, NI, NI, NI}, r5, xv;
#pragma unroll
  for (int d = -1; d <= 1; ++d) {
    int bb = beta + d;
    if ((unsigned)bb >= 64u) continue;
    float4 f = *(const float4*)(base + (size_t)bb * CH);
    if (d == 0) xv = f;
    r3.x = fmaxf(r3.x, f.x); r3.y = fmaxf(r3.y, f.y);
    r3.z = fmaxf(r3.z, f.z); r3.w = fmaxf(r3.w, f.w);
  }
  r5 = r3;
#pragma unroll
  for (int d = -2; d <= 2; d += 4) {
    int bb = beta + d;
    if ((unsigned)bb >= 64u) continue;
    float4 f = *(const float4*)(base + (size_t)bb * CH);
    r5.x = fmaxf(r5.x, f.x); r5.y = fmaxf(r5.y, f.y);
    r5.z = fmaxf(r5.z, f.z); r5.w = fmaxf(r5.w, f.w);
  }
  size_t o = (size_t)loc * CH + c0;
  uint2 p3, p5, px;
  p3.x = f2bf(r3.x) | ((unsigned)f2bf(r3.y) << 16);
  p3.y = f2bf(r3.z) | ((unsigned)f2bf(r3.w) << 16);
  p5.x = f2bf(r5.x) | ((unsigned)f2bf(r5.y) << 16);
  p5.y = f2bf(r5.z) | ((unsigned)f2bf(r5.w) << 16);
  px.x = f2bf(xv.x) | ((unsigned)f2bf(xv.y) << 16);
  px.y = f2bf(xv.z) | ((unsigned)f2bf(xv.w) << 16);
  *(uint2*)(rm3 + o) = p3;
  *(uint2*)(rm5 + o) = p5;
  *(uint2*)(xb + o) = px;
}

// ---------------------------------------------------------------------------
// v = xb @ Wv + bv -> bf16 [loc][256]. 128x128 tile, BK=64, dbuf frag LDS.
// 512 threads / 8 waves.
__global__ __launch_bounds__(512) void k_gemm_v(
    const unsigned short* __restrict__ xb, const unsigned short* __restrict__ wvp,
    const float* __restrict__ bv, unsigned short* __restrict__ v) {
  __shared__ unsigned short sA[2][16 * 512];
  __shared__ unsigned short sB[2][16 * 512];
  int tid = threadIdx.x, lane = tid & 63, w = tid >> 6;
  int r0 = (blockIdx.x >> 1) * 128;
  int nc0 = (blockIdx.x & 1) * 128;
  int mh = w >> 1, nq = w & 1;
  floatx4 acc[2][4];
#pragma unroll
  for (int mt = 0; mt < 2; ++mt)
#pragma unroll
    for (int nf = 0; nf < 4; ++nf) acc[mt][nf] = (floatx4)(0.f);
#pragma unroll
  for (int f = 0; f < 4; ++f) {
    int fg = w * 4 + f;
    if (fg < 16) {
      int mt16 = fg >> 1, ks = fg & 1;
      gl_lds16(xb + (size_t)(r0 + mt16 * 16 + (lane & 15)) * CH + ks * 32 + (lane >> 4) * 8,
               &sA[0][fg * 512]);
    } else {
      int g = fg - 16, nf16 = g >> 1, ks = g & 1;
      gl_lds16(wvp + ((size_t)((nc0 >> 4) + nf16) * 8 + ks) * 512 + lane * 8,
               &sB[0][g * 512]);
    }
  }
  __syncthreads();
  for (int kt = 0; kt < 4; ++kt) {
    int cur = kt & 1;
    if (kt < 3) {
      int kn = kt + 1, nb = kn & 1, kkn = kn * 64;
#pragma unroll
      for (int f = 0; f < 4; ++f) {
        int fg = w * 4 + f;
        if (fg < 16) {
          int mt16 = fg >> 1, ks = fg & 1;
          gl_lds16(xb + (size_t)(r0 + mt16 * 16 + (lane & 15)) * CH + kkn + ks * 32 + (lane >> 4) * 8,
                   &sA[nb][fg * 512]);
        } else {
          int g = fg - 16, nf16 = g >> 1, ks = g & 1;
          gl_lds16(wvp + ((size_t)((nc0 >> 4) + nf16) * 8 + kn * 2 + ks) * 512 + lane * 8,
                   &sB[nb][g * 512]);
        }
      }
    }
#pragma unroll
    for (int ks = 0; ks < 2; ++ks) {
      short8 af[2], bf[4];
#pragma unroll
      for (int mt = 0; mt < 2; ++mt)
        af[mt] = *(const short8*)&sA[cur][(((mh * 2 + mt) << 1) + ks) * 512 + lane * 8];
#pragma unroll
      for (int nf = 0; nf < 4; ++nf)
        bf[nf] = *(const short8*)&sB[cur][(((nq * 4 + nf) << 1) + ks) * 512 + lane * 8];
#pragma unroll
      for (int mt = 0; mt < 2; ++mt)
#pragma unroll
        for (int nf = 0; nf < 4; ++nf)
          acc[mt][nf] = __builtin_amdgcn_mfma_f32_16x16x32_bf16(af[mt], bf[nf], acc[mt][nf], 0, 0, 0);
    }
    __syncthreads();
  }
#pragma unroll
  for (int nf = 0; nf < 4; ++nf) {
    int c = nc0 + nq * 64 + nf * 16 + (lane & 15);
    float bb = bv[c];
#pragma unroll
    for (int mt = 0; mt < 2; ++mt) {
      int crow = r0 + mh * 32 + mt * 16 + (lane >> 4) * 4;
#pragma unroll
      for (int i = 0; i < 4; ++i)
        v[(size_t)(crow + i) * CH + c] = f2bf(acc[mt][nf][i] + bb);
    }
  }
}

// ---------------------------------------------------------------------------
// logits = xb @ Wa + ba (96 cols, 81 valid) -> softmax9 -> A bf16 [loc][81]
__global__ __launch_bounds__(256) void k_gemm_a(
    const unsigned short* __restrict__ xb, const unsigned short* __restrict__ wap,
    const float* __restrict__ ba, unsigned short* __restrict__ A) {
  __shared__ float lg[64][96];
  int tid = threadIdx.x, lane = tid & 63, w = tid >> 6;
  int mtile = blockIdx.x * 4 + w;
  int r0 = mtile * 16;
  floatx4 acc[6];
#pragma unroll
  for (int i = 0; i < 6; ++i) acc[i] = (floatx4)(0.f);
  const unsigned short* abase = xb + (size_t)(r0 + (lane & 15)) * CH + (lane >> 4) * 8;
  for (int ks = 0; ks < 8; ++ks) {
    short8 af = *(const short8*)(abase + ks * 32);
#pragma unroll
    for (int nf = 0; nf < 6; ++nf) {
      short8 bfr = *(const short8*)(wap + ((size_t)(nf * 8) + ks) * 512 + lane * 8);
      acc[nf] = __builtin_amdgcn_mfma_f32_16x16x32_bf16(af, bfr, acc[nf], 0, 0, 0);
    }
  }
  int lrow = w * 16 + (lane >> 4) * 4;
#pragma unroll
  for (int nf = 0; nf < 6; ++nf) {
    int c = nf * 16 + (lane & 15);
    float bb = (c < 81) ? ba[c] : 0.f;
#pragma unroll
    for (int i = 0; i < 4; ++i)
      lg[lrow + i][c] = acc[nf][i] + bb;
  }
  __syncthreads();
  int loc0 = blockIdx.x * 64;
  for (int it = 0; it < 3; ++it) {
    int idx = tid + it * 256;
    if (idx < 576) {
      int row = idx / 9, g = idx % 9;
      float vals[9];
#pragma unroll
      for (int q = 0; q < 9; ++q) vals[q] = lg[row][g * 9 + q];
      float m = vals[0];
#pragma unroll
      for (int q = 1; q < 9; ++q) m = fmaxf(m, vals[q]);
      float s = 0.f;
#pragma unroll
      for (int q = 0; q < 9; ++q) { vals[q] = __expf(vals[q] - m); s += vals[q]; }
      float inv = 1.f / s;
      unsigned short* o = A + (size_t)(loc0 + row) * 81 + g * 9;
#pragma unroll
      for (int q = 0; q < 9; ++q) o[q] = f2bf(vals[q] * inv);
    }
  }
}

// ---------------------------------------------------------------------------
// attention gather + col-max of rm3/rm5 -> cat [loc][512] bf16
// 512 threads: 8 betas x 64 ch-threads (4 ch each). XCD-swizzled blockIdx.
// bf16 LDS window (8B-stride taps: conflict-free).
__global__ __launch_bounds__(512) void k_attn(
    const unsigned short* __restrict__ A, const unsigned short* __restrict__ v,
    const unsigned short* __restrict__ rm3, const unsigned short* __restrict__ rm5,
    unsigned short* __restrict__ cat) {
  __shared__ unsigned short vs[5 * 12 * CH];   // 30720 B; head doubles as a_s
  __shared__ float w5_s[8][25];                // 800 B
  float* a_sf = (float*)vs;                    // [8][81] f32 (dead after fold)
  int tid = threadIdx.x;
  int bid = (blockIdx.x & 7) * 512 + (blockIdx.x >> 3);
  int loc0 = bid * 8;
  int b = loc0 >> 12, alpha = (loc0 >> 6) & 63, beta0 = loc0 & 63;
  for (int idx = tid; idx < 8 * 81; idx += 512) {
    int li = idx / 81, t = idx - li * 81;
    int ij = t / 9, i = ij / 3, j = ij % 3;
    int lh = beta0 + li + 1 - i;
    int lw = alpha + 1 - j;
    float val = 0.f;
    if ((unsigned)lh < 64u && (unsigned)lw < 64u)
      val = bf2f(A[(size_t)(b * 4096 + lh * 64 + lw) * 81 + t]);
    a_sf[li * 81 + t] = val;
  }
  __syncthreads();
  if (tid < 200) {
    int li = tid / 25, o = tid - li * 25;
    int dh = o / 5 - 2, dw = o % 5 - 2;
    float s = 0.f;
    int jlo = dh < 0 ? -dh : 0, jhi = dh > 0 ? 2 - dh : 2;
    int ilo = dw < 0 ? -dw : 0, ihi = dw > 0 ? 2 - dw : 2;
    for (int j = jlo; j <= jhi; ++j)
      for (int i = ilo; i <= ihi; ++i)
        s += a_sf[li * 81 + (i * 3 + j) * 9 + ((i + dw) * 3 + (j + dh))];
    w5_s[li][o] = s;
  }
  __syncthreads();
  const unsigned short* vb = v + (size_t)b * 4096 * CH;
  for (int i = tid; i < 1920; i += 512) {
    int row = i / 384, rem = i - row * 384, col = rem >> 5, ch8 = rem & 31;
    int hv = alpha - 2 + row, wv = beta0 - 2 + col;
    uint4 val = {0u, 0u, 0u, 0u};
    if ((unsigned)hv < 64u && (unsigned)wv < 64u)
      val = *(const uint4*)(vb + (size_t)(hv * 64 + wv) * CH + ch8 * 8);
    *(uint4*)(vs + (size_t)(row * 12 + col) * CH + ch8 * 8) = val;
  }
  __syncthreads();
  int li = tid >> 6, tc = tid & 63, c0 = tc * 4;
  int beta = beta0 + li;
  float m1[4], m2[4];
#pragma unroll
  for (int q = 0; q < 4; ++q) { m1[q] = -INFINITY; m2[q] = -INFINITY; }
#pragma unroll
  for (int da = -2; da <= 2; ++da) {
    int aa = alpha + da;
    if ((unsigned)aa >= 64u) continue;
    size_t ro = (size_t)((b * 64 + aa) * 64 + beta) * CH + c0;
    uint2 p5 = *(const uint2*)(rm5 + ro);
    m2[0] = fmaxf(m2[0], bflo(p5.x)); m2[1] = fmaxf(m2[1], bfhi(p5.x));
    m2[2] = fmaxf(m2[2], bflo(p5.y)); m2[3] = fmaxf(m2[3], bfhi(p5.y));
    if (da >= -1 && da <= 1) {
      uint2 p3 = *(const uint2*)(rm3 + ro);
      m1[0] = fmaxf(m1[0], bflo(p3.x)); m1[1] = fmaxf(m1[1], bfhi(p3.x));
      m1[2] = fmaxf(m1[2], bflo(p3.y)); m1[3] = fmaxf(m1[3], bfhi(p3.y));
    }
  }
  float acc[4] = {0.f, 0.f, 0.f, 0.f};
#pragma unroll
  for (int dh = 0; dh < 5; ++dh) {
#pragma unroll
    for (int dw = 0; dw < 5; ++dw) {
      float wgt = w5_s[li][dh * 5 + dw];
      uint2 pk = *(const uint2*)(vs + (size_t)(dh * 12 + li + dw) * CH + c0);
      acc[0] = fmaf(wgt, bflo(pk.x), acc[0]);
      acc[1] = fmaf(wgt, bfhi(pk.x), acc[1]);
      acc[2] = fmaf(wgt, bflo(pk.y), acc[2]);
      acc[3] = fmaf(wgt, bfhi(pk.y), acc[3]);
    }
  }
  unsigned short u1[4], u2[4];
#pragma unroll
  for (int q = 0; q < 4; ++q) {
    float x1v = fmaxf(fmaxf(acc[q], 0.f) + m1[q], 0.f);
    float x2v = fmaxf(x1v + m2[q], 0.f);
    u1[q] = f2bf(x1v);
    u2[q] = f2bf(x2v);
  }
  unsigned short* cp = cat + (size_t)(loc0 + li) * 512 + c0;
  uint2 pk1, pk2;
  pk1.x = u1[0] | ((unsigned)u1[1] << 16); pk1.y = u1[2] | ((unsigned)u1[3] << 16);
  pk2.x = u2[0] | ((unsigned)u2[1] << 16); pk2.y = u2[2] | ((unsigned)u2[3] << 16);
  *(uint2*)(cp) = pk1;
  *(uint2*)(cp + 256) = pk2;
}

// ---------------------------------------------------------------------------
// xfu = relu(cat @ Wfu + bfu); outb = bf16(x + xfu) transposed; BN sums (16-banked).
// 128x128 tile, BK=64, K=512, dbuf frag LDS. 512 threads / 8 waves.
__global__ __launch_bounds__(512) void k_fuse(
    const unsigned short* __restrict__ xb, const unsigned short* __restrict__ cat,
    const unsigned short* __restrict__ wfp, const float* __restrict__ bfu,
    unsigned short* __restrict__ outb, float* __restrict__ sums16) {
  __shared__ unsigned short sA[2][16 * 512];
  __shared__ unsigned short sB[2][16 * 512];
  __shared__ float bsum[512];
  int tid = threadIdx.x, lane = tid & 63, w = tid >> 6;
  for (int i = tid; i < 512; i += 512) bsum[i] = 0.f;
  int r0 = (blockIdx.x >> 1) * 128;
  int nc0 = (blockIdx.x & 1) * 128;
  int mh = w >> 1, nq = w & 1;
  floatx4 acc[2][4];
#pragma unroll
  for (int mt = 0; mt < 2; ++mt)
#pragma unroll
    for (int nf = 0; nf < 4; ++nf) acc[mt][nf] = (floatx4)(0.f);
#pragma unroll
  for (int f = 0; f < 4; ++f) {
    int fg = w * 4 + f;
    if (fg < 16) {
      int mt16 = fg >> 1, ks = fg & 1;
      gl_lds16(cat + (size_t)(r0 + mt16 * 16 + (lane & 15)) * 512 + ks * 32 + (lane >> 4) * 8,
               &sA[0][fg * 512]);
    } else {
      int g = fg - 16, nf16 = g >> 1, ks = g & 1;
      gl_lds16(wfp + ((size_t)((nc0 >> 4) + nf16) * 16 + ks) * 512 + lane * 8,
               &sB[0][g * 512]);
    }
  }
  __syncthreads();
  for (int kt = 0; kt < 8; ++kt) {
    int cur = kt & 1;
    if (kt < 7) {
      int kn = kt + 1, nb = kn & 1, kkn = kn * 64;
#pragma unroll
      for (int f = 0; f < 4; ++f) {
        int fg = w * 4 + f;
        if (fg < 16) {
          int mt16 = fg >> 1, ks = fg & 1;
          gl_lds16(cat + (size_t)(r0 + mt16 * 16 + (lane & 15)) * 512 + kkn + ks * 32 + (lane >> 4) * 8,
                   &sA[nb][fg * 512]);
        } else {
          int g = fg - 16, nf16 = g >> 1, ks = g & 1;
          gl_lds16(wfp + ((size_t)((nc0 >> 4) + nf16) * 16 + kn * 2 + ks) * 512 + lane * 8,
                   &sB[nb][g * 512]);
        }
      }
    }
#pragma unroll
    for (int ks = 0; ks < 2; ++ks) {
      short8 af[2], bf[4];
#pragma unroll
      for (int mt = 0; mt < 2; ++mt)
        af[mt] = *(const short8*)&sA[cur][(((mh * 2 + mt) << 1) + ks) * 512 + lane * 8];
#pragma unroll
      for (int nf = 0; nf < 4; ++nf)
        bf[nf] = *(const short8*)&sB[cur][(((nq * 4 + nf) << 1) + ks) * 512 + lane * 8];
#pragma unroll
      for (int mt = 0; mt < 2; ++mt)
#pragma unroll
        for (int nf = 0; nf < 4; ++nf)
          acc[mt][nf] = __builtin_amdgcn_mfma_f32_16x16x32_bf16(af[mt], bf[nf], acc[mt][nf], 0, 0, 0);
    }
    __syncthreads();
  }
#pragma unroll
  for (int nf = 0; nf < 4; ++nf) {
    int c = nc0 + nq * 64 + nf * 16 + (lane & 15);
    float bb = bfu[c];
    float s = 0.f, ss = 0.f;
#pragma unroll
    for (int mt = 0; mt < 2; ++mt) {
      int crow = r0 + mh * 32 + mt * 16 + (lane >> 4) * 4;
#pragma unroll
      for (int i = 0; i < 4; ++i) {
        int r = crow + i;
        float xv = bf2f(xb[(size_t)r * CH + c]);
        float o = xv + fmaxf(acc[mt][nf][i] + bb, 0.f);
        int b_ = r >> 12, al = (r >> 6) & 63, be = r & 63;
        outb[((size_t)(b_ * 64 + be) * 64 + al) * CH + c] = f2bf(o);
        s += o; ss += o * o;
      }
    }
    s += __shfl_xor(s, 16);  s += __shfl_xor(s, 32);
    ss += __shfl_xor(ss, 16); ss += __shfl_xor(ss, 32);
    if (lane < 16) {
      atomicAdd(&bsum[c & 255], s);
      atomicAdd(&bsum[256 + (c & 255)], ss);
    }
  }
  __syncthreads();
  float* bank = sums16 + (size_t)(blockIdx.x & 15) * 512;
  for (int i = tid; i < 512; i += 512) atomicAdd(&bank[i], bsum[i]);
}

// ---------------------------------------------------------------------------
__global__ void k_bnprep(const float* __restrict__ sums16,
                         const float* __restrict__ gamma,
                         const float* __restrict__ beta_,
                         float* __restrict__ sc) {
  int c = threadIdx.x;
  float s = 0.f, ss = 0.f;
#pragma unroll
  for (int bk = 0; bk < 16; ++bk) {
    s += sums16[(size_t)bk * 512 + c];
    ss += sums16[(size_t)bk * 512 + 256 + c];
  }
  const float inv_n = 1.f / (float)NLOC;
  float mean = s * inv_n;
  float var = ss * inv_n - mean * mean;
  float scale = gamma[c] * rsqrtf(var + 1e-5f);
  sc[c] = scale;
  sc[256 + c] = beta_[c] - mean * scale;
}

// ---------------------------------------------------------------------------
__global__ __launch_bounds__(256) void k_bn(
    const unsigned short* __restrict__ outb, float* __restrict__ outp,
    const float* __restrict__ sc, int n8) {
  __shared__ float s[512];
  const int tid = threadIdx.x;
  for (int i = tid; i < 512; i += 256) s[i] = sc[i];
  __syncthreads();
  for (int i = blockIdx.x * 256 + tid; i < n8; i += gridDim.x * 256) {
    uint4 pk = ((const uint4*)outb)[i];
    int c0 = (i & 31) * 8;
    float4 o0, o1;
    o0.x = bflo(pk.x) * s[c0 + 0] + s[256 + c0 + 0];
    o0.y = bfhi(pk.x) * s[c0 + 1] + s[256 + c0 + 1];
    o0.z = bflo(pk.y) * s[c0 + 2] + s[256 + c0 + 2];
    o0.w = bfhi(pk.y) * s[c0 + 3] + s[256 + c0 + 3];
    o1.x = bflo(pk.z) * s[c0 + 4] + s[256 + c0 + 4];
    o1.y = bfhi(pk.z) * s[c0 + 5] + s[256 + c0 + 5];
    o1.z = bflo(pk.w) * s[c0 + 6] + s[256 + c0 + 6];
    o1.w = bfhi(pk.w) * s[c0 + 7] + s[256 + c0 + 7];
    ((float4*)outp)[i * 2] = o0;
    ((float4*)outp)[i * 2 + 1] = o1;
  }
}

// ---------------------------------------------------------------------------
extern "C" void kernel_launch(void* const* d_in, const int* in_sizes, int n_in,
                              void* d_out, int out_size, void* d_ws, size_t ws_size,
                              hipStream_t stream) {
  const float* x     = (const float*)d_in[0];
  const float* Wv    = (const float*)d_in[1];
  const float* bv    = (const float*)d_in[2];
  const float* Wa    = (const float*)d_in[3];
  const float* ba    = (const float*)d_in[4];
  const float* Wfu   = (const float*)d_in[5];
  const float* bfu   = (const float*)d_in[6];
  const float* gamma = (const float*)d_in[7];
  const float* beta_ = (const float*)d_in[8];
  float* out = (float*)d_out;

  float* sums16 = (float*)d_ws;                             // 16*512 f32
  float* sc     = sums16 + 16 * 512;                        // 512 f32
  unsigned short* wp   = (unsigned short*)(sc + 512);       // 432*512 bf16
  unsigned short* wvp  = wp;
  unsigned short* wfp  = wp + (size_t)128 * 512;
  unsigned short* wap  = wp + (size_t)384 * 512;
  unsigned short* vbuf = wp + (size_t)432 * 512;            // NLOC*256 bf16 (v; reused as outb)
  unsigned short* Abuf = vbuf + (size_t)NLOC * CH;          // NLOC*81 bf16
  unsigned short* cat  = Abuf + (size_t)NLOC * 81;          // NLOC*512 bf16
  unsigned short* rm3  = cat + (size_t)NLOC * 512;          // NLOC*256 bf16
  unsigned short* rm5  = rm3 + (size_t)NLOC * CH;           // NLOC*256 bf16
  unsigned short* xb   = rm5 + (size_t)NLOC * CH;           // NLOC*256 bf16
  unsigned short* outb = vbuf;  // v dead after k_attn -> reuse for pre-BN out

  hipMemsetAsync(sums16, 0, 16 * 512 * sizeof(float), stream);

  k_pack_w<<<432, 64, 0, stream>>>(Wv, Wa, Wfu, wp);
  k_pool<<<8192, 256, 0, stream>>>(x, rm3, rm5, xb);
  k_gemm_v<<<512, 512, 0, stream>>>(xb, wvp, bv, vbuf);
  k_gemm_a<<<512, 256, 0, stream>>>(xb, wap, ba, Abuf);
  k_attn<<<4096, 512, 0, stream>>>(Abuf, vbuf, rm3, rm5, cat);
  k_fuse<<<512, 512, 0, stream>>>(xb, cat, wfp, bfu, outb, sums16);
  k_bnprep<<<1, 256, 0, stream>>>(sums16, gamma, beta_, sc);
  k_bn<<<2048, 256, 0, stream>>>(outb, out, sc, NLOC * CH / 8);
}

// Round 22
// 117.570 us; speedup vs baseline: 1.1325x; 1.0103x over previous
//
#include <hip/hip_runtime.h>
#include <math.h>

#define NLOC 32768
#define CH 256

typedef __attribute__((ext_vector_type(8))) short short8;
typedef __attribute__((ext_vector_type(4))) float floatx4;

__device__ inline unsigned short f2bf(float x) {
  union { float f; unsigned u; } c; c.f = x;
  unsigned r = c.u + 0x7FFFu + ((c.u >> 16) & 1u);
  return (unsigned short)(r >> 16);
}
__device__ inline float bflo(unsigned u) {
  union { unsigned u; float f; } c; c.u = u << 16; return c.f;
}
__device__ inline float bfhi(unsigned u) {
  union { unsigned u; float f; } c; c.u = u & 0xFFFF0000u; return c.f;
}
__device__ inline float bf2f(unsigned short u) {
  union { unsigned u; float f; } c; c.u = (unsigned)u << 16; return c.f;
}

// async global->LDS 16B: lds dest is wave-uniform base (+lane*16 by HW)
__device__ __forceinline__ void gl_lds16(const void* g, void* l) {
  __builtin_amdgcn_global_load_lds(
      (const __attribute__((address_space(1))) unsigned int*)g,
      (__attribute__((address_space(3))) unsigned int*)l, 16, 0, 0);
}

// ---------------------------------------------------------------------------
// P0: pack Wv/Wfu/Wa(->96 cols, zero-pad) to bf16 MFMA B-fragment order.
__global__ __launch_bounds__(64) void k_pack_w(
    const float* __restrict__ Wv, const float* __restrict__ Wa,
    const float* __restrict__ Wfu, unsigned short* __restrict__ wp) {
  int fid = blockIdx.x;
  int l = threadIdx.x;
  const float* W; int ldn, nvalid, nf, ks;
  if (fid < 128)      { W = Wv;  ldn = 256; nvalid = 256; nf = fid >> 3; ks = fid & 7; }
  else if (fid < 384) { int f = fid - 128; W = Wfu; ldn = 256; nvalid = 256; nf = f >> 4; ks = f & 15; }
  else                { int f = fid - 384; W = Wa;  ldn = 81;  nvalid = 81;  nf = f >> 3; ks = f & 7; }
  unsigned short* dst = wp + (size_t)fid * 512;
  int c = nf * 16 + (l & 15);
  int k0 = ks * 32 + (l >> 4) * 8;
  unsigned short u[8];
#pragma unroll
  for (int j = 0; j < 8; ++j)
    u[j] = (c < nvalid) ? f2bf(W[(size_t)(k0 + j) * ldn + c]) : (unsigned short)0;
  uint4 pk;
  pk.x = u[0] | ((unsigned)u[1] << 16);
  pk.y = u[2] | ((unsigned)u[3] << 16);
  pk.z = u[4] | ((unsigned)u[5] << 16);
  pk.w = u[6] | ((unsigned)u[7] << 16);
  *(uint4*)(dst + l * 8) = pk;
}

// ---------------------------------------------------------------------------
// Separable maxpool row-pass along beta + bf16 cast of x. One thread per (loc,c4)
__global__ __launch_bounds__(256) void k_pool(
    const float* __restrict__ x, unsigned short* __restrict__ rm3,
    unsigned short* __restrict__ rm5, unsigned short* __restrict__ xb) {
  int tid = threadIdx.x;
  int loc = blockIdx.x * 4 + (tid >> 6);
  int beta = loc & 63;
  int c0 = (tid & 63) * 4;
  const float* base = x + ((size_t)loc - beta) * CH + c0;
  const float NI = -INFINITY;
  float4 r3 = {NI, NI, NI, NI}, r5, xv;
#pragma unroll
  for (int d = -1; d <= 1; ++d) {
    int bb = beta + d;
    if ((unsigned)bb >= 64u) continue;
    float4 f = *(const float4*)(base + (size_t)bb * CH);
    if (d == 0) xv = f;
    r3.x = fmaxf(r3.x, f.x); r3.y = fmaxf(r3.y, f.y);
    r3.z = fmaxf(r3.z, f.z); r3.w = fmaxf(r3.w, f.w);
  }
  r5 = r3;
#pragma unroll
  for (int d = -2; d <= 2; d += 4) {
    int bb = beta + d;
    if ((unsigned)bb >= 64u) continue;
    float4 f = *(const float4*)(base + (size_t)bb * CH);
    r5.x = fmaxf(r5.x, f.x); r5.y = fmaxf(r5.y, f.y);
    r5.z = fmaxf(r5.z, f.z); r5.w = fmaxf(r5.w, f.w);
  }
  size_t o = (size_t)loc * CH + c0;
  uint2 p3, p5, px;
  p3.x = f2bf(r3.x) | ((unsigned)f2bf(r3.y) << 16);
  p3.y = f2bf(r3.z) | ((unsigned)f2bf(r3.w) << 16);
  p5.x = f2bf(r5.x) | ((unsigned)f2bf(r5.y) << 16);
  p5.y = f2bf(r5.z) | ((unsigned)f2bf(r5.w) << 16);
  px.x = f2bf(xv.x) | ((unsigned)f2bf(xv.y) << 16);
  px.y = f2bf(xv.z) | ((unsigned)f2bf(xv.w) << 16);
  *(uint2*)(rm3 + o) = p3;
  *(uint2*)(rm5 + o) = p5;
  *(uint2*)(xb + o) = px;
}

// ---------------------------------------------------------------------------
// v = xb @ Wv + bv -> bf16 [loc][256]. 128x128 tile, BK=64, dbuf frag LDS.
// 512 threads / 8 waves.
__global__ __launch_bounds__(512) void k_gemm_v(
    const unsigned short* __restrict__ xb, const unsigned short* __restrict__ wvp,
    const float* __restrict__ bv, unsigned short* __restrict__ v) {
  __shared__ unsigned short sA[2][16 * 512];
  __shared__ unsigned short sB[2][16 * 512];
  int tid = threadIdx.x, lane = tid & 63, w = tid >> 6;
  int r0 = (blockIdx.x >> 1) * 128;
  int nc0 = (blockIdx.x & 1) * 128;
  int mh = w >> 1, nq = w & 1;
  floatx4 acc[2][4];
#pragma unroll
  for (int mt = 0; mt < 2; ++mt)
#pragma unroll
    for (int nf = 0; nf < 4; ++nf) acc[mt][nf] = (floatx4)(0.f);
#pragma unroll
  for (int f = 0; f < 4; ++f) {
    int fg = w * 4 + f;
    if (fg < 16) {
      int mt16 = fg >> 1, ks = fg & 1;
      gl_lds16(xb + (size_t)(r0 + mt16 * 16 + (lane & 15)) * CH + ks * 32 + (lane >> 4) * 8,
               &sA[0][fg * 512]);
    } else {
      int g = fg - 16, nf16 = g >> 1, ks = g & 1;
      gl_lds16(wvp + ((size_t)((nc0 >> 4) + nf16) * 8 + ks) * 512 + lane * 8,
               &sB[0][g * 512]);
    }
  }
  __syncthreads();
  for (int kt = 0; kt < 4; ++kt) {
    int cur = kt & 1;
    if (kt < 3) {
      int kn = kt + 1, nb = kn & 1, kkn = kn * 64;
#pragma unroll
      for (int f = 0; f < 4; ++f) {
        int fg = w * 4 + f;
        if (fg < 16) {
          int mt16 = fg >> 1, ks = fg & 1;
          gl_lds16(xb + (size_t)(r0 + mt16 * 16 + (lane & 15)) * CH + kkn + ks * 32 + (lane >> 4) * 8,
                   &sA[nb][fg * 512]);
        } else {
          int g = fg - 16, nf16 = g >> 1, ks = g & 1;
          gl_lds16(wvp + ((size_t)((nc0 >> 4) + nf16) * 8 + kn * 2 + ks) * 512 + lane * 8,
                   &sB[nb][g * 512]);
        }
      }
    }
#pragma unroll
    for (int ks = 0; ks < 2; ++ks) {
      short8 af[2], bf[4];
#pragma unroll
      for (int mt = 0; mt < 2; ++mt)
        af[mt] = *(const short8*)&sA[cur][(((mh * 2 + mt) << 1) + ks) * 512 + lane * 8];
#pragma unroll
      for (int nf = 0; nf < 4; ++nf)
        bf[nf] = *(const short8*)&sB[cur][(((nq * 4 + nf) << 1) + ks) * 512 + lane * 8];
#pragma unroll
      for (int mt = 0; mt < 2; ++mt)
#pragma unroll
        for (int nf = 0; nf < 4; ++nf)
          acc[mt][nf] = __builtin_amdgcn_mfma_f32_16x16x32_bf16(af[mt], bf[nf], acc[mt][nf], 0, 0, 0);
    }
    __syncthreads();
  }
#pragma unroll
  for (int nf = 0; nf < 4; ++nf) {
    int c = nc0 + nq * 64 + nf * 16 + (lane & 15);
    float bb = bv[c];
#pragma unroll
    for (int mt = 0; mt < 2; ++mt) {
      int crow = r0 + mh * 32 + mt * 16 + (lane >> 4) * 4;
#pragma unroll
      for (int i = 0; i < 4; ++i)
        v[(size_t)(crow + i) * CH + c] = f2bf(acc[mt][nf][i] + bb);
    }
  }
}

// ---------------------------------------------------------------------------
// logits = xb @ Wa + ba (96 cols, 81 valid) -> softmax9 -> A bf16 [loc][81]
__global__ __launch_bounds__(256) void k_gemm_a(
    const unsigned short* __restrict__ xb, const unsigned short* __restrict__ wap,
    const float* __restrict__ ba, unsigned short* __restrict__ A) {
  __shared__ float lg[64][96];
  int tid = threadIdx.x, lane = tid & 63, w = tid >> 6;
  int mtile = blockIdx.x * 4 + w;
  int r0 = mtile * 16;
  floatx4 acc[6];
#pragma unroll
  for (int i = 0; i < 6; ++i) acc[i] = (floatx4)(0.f);
  const unsigned short* abase = xb + (size_t)(r0 + (lane & 15)) * CH + (lane >> 4) * 8;
  for (int ks = 0; ks < 8; ++ks) {
    short8 af = *(const short8*)(abase + ks * 32);
#pragma unroll
    for (int nf = 0; nf < 6; ++nf) {
      short8 bfr = *(const short8*)(wap + ((size_t)(nf * 8) + ks) * 512 + lane * 8);
      acc[nf] = __builtin_amdgcn_mfma_f32_16x16x32_bf16(af, bfr, acc[nf], 0, 0, 0);
    }
  }
  int lrow = w * 16 + (lane >> 4) * 4;
#pragma unroll
  for (int nf = 0; nf < 6; ++nf) {
    int c = nf * 16 + (lane & 15);
    float bb = (c < 81) ? ba[c] : 0.f;
#pragma unroll
    for (int i = 0; i < 4; ++i)
      lg[lrow + i][c] = acc[nf][i] + bb;
  }
  __syncthreads();
  int loc0 = blockIdx.x * 64;
  for (int it = 0; it < 3; ++it) {
    int idx = tid + it * 256;
    if (idx < 576) {
      int row = idx / 9, g = idx % 9;
      float vals[9];
#pragma unroll
      for (int q = 0; q < 9; ++q) vals[q] = lg[row][g * 9 + q];
      float m = vals[0];
#pragma unroll
      for (int q = 1; q < 9; ++q) m = fmaxf(m, vals[q]);
      float s = 0.f;
#pragma unroll
      for (int q = 0; q < 9; ++q) { vals[q] = __expf(vals[q] - m); s += vals[q]; }
      float inv = 1.f / s;
      unsigned short* o = A + (size_t)(loc0 + row) * 81 + g * 9;
#pragma unroll
      for (int q = 0; q < 9; ++q) o[q] = f2bf(vals[q] * inv);
    }
  }
}

// ---------------------------------------------------------------------------
// attention gather + col-max of rm3/rm5 -> cat [loc][512] bf16
// 16-beta blocks: 512 threads = 16 betas x 32 ch-threads (8 ch each).
// bf16 LDS window [5][20][256] = 51.2KB; a_s overlays head. XCD swizzle (2048).
__global__ __launch_bounds__(512) void k_attn(
    const unsigned short* __restrict__ A, const unsigned short* __restrict__ v,
    const unsigned short* __restrict__ rm3, const unsigned short* __restrict__ rm5,
    unsigned short* __restrict__ cat) {
  __shared__ unsigned short vs[5 * 20 * CH];   // 51200 B; head doubles as a_s
  __shared__ float w5_s[16][25];               // 1600 B
  float* a_sf = (float*)vs;                    // [16][81] f32 = 5184 B (dead after fold)
  int tid = threadIdx.x;
  // XCD swizzle: nwg=2048, 8 XCDs -> chunks of 256
  int bid = (blockIdx.x & 7) * 256 + (blockIdx.x >> 3);
  int loc0 = bid * 16;
  int b = loc0 >> 12, alpha = (loc0 >> 6) & 63, beta0 = loc0 & 63;
  // 1) stage A rows (16 x 81)
  for (int idx = tid; idx < 16 * 81; idx += 512) {
    int li = idx / 81, t = idx - li * 81;
    int ij = t / 9, i = ij / 3, j = ij % 3;
    int lh = beta0 + li + 1 - i;
    int lw = alpha + 1 - j;
    float val = 0.f;
    if ((unsigned)lh < 64u && (unsigned)lw < 64u)
      val = bf2f(A[(size_t)(b * 4096 + lh * 64 + lw) * 81 + t]);
    a_sf[li * 81 + t] = val;
  }
  __syncthreads();
  // 2) fold 81 -> 25 per loc
  if (tid < 400) {
    int li = tid / 25, o = tid - li * 25;
    int dh = o / 5 - 2, dw = o % 5 - 2;
    float s = 0.f;
    int jlo = dh < 0 ? -dh : 0, jhi = dh > 0 ? 2 - dh : 2;
    int ilo = dw < 0 ? -dw : 0, ihi = dw > 0 ? 2 - dw : 2;
    for (int j = jlo; j <= jhi; ++j)
      for (int i = ilo; i <= ihi; ++i)
        s += a_sf[li * 81 + (i * 3 + j) * 9 + ((i + dw) * 3 + (j + dh))];
    w5_s[li][o] = s;
  }
  __syncthreads();   // a_s dead
  // 3) stage v window [5][20][256] bf16 (overwrites a_s region)
  const unsigned short* vb = v + (size_t)b * 4096 * CH;
  for (int i = tid; i < 3200; i += 512) {
    int row = i / 640, rem = i - row * 640, col = rem >> 5, ch8 = rem & 31;
    int hv = alpha - 2 + row, wv = beta0 - 2 + col;
    uint4 val = {0u, 0u, 0u, 0u};
    if ((unsigned)hv < 64u && (unsigned)wv < 64u)
      val = *(const uint4*)(vb + (size_t)(hv * 64 + wv) * CH + ch8 * 8);
    *(uint4*)(vs + (size_t)(row * 20 + col) * CH + ch8 * 8) = val;
  }
  __syncthreads();
  // 4) per-thread: li = tid>>5 (beta), 8 channels
  int li = tid >> 5, tc = tid & 31, c0 = tc * 8;
  int beta = beta0 + li;
  float m1[8], m2[8];
#pragma unroll
  for (int q = 0; q < 8; ++q) { m1[q] = -INFINITY; m2[q] = -INFINITY; }
#pragma unroll
  for (int da = -2; da <= 2; ++da) {
    int aa = alpha + da;
    if ((unsigned)aa >= 64u) continue;
    size_t ro = (size_t)((b * 64 + aa) * 64 + beta) * CH + c0;
    uint4 p5 = *(const uint4*)(rm5 + ro);
    m2[0] = fmaxf(m2[0], bflo(p5.x)); m2[1] = fmaxf(m2[1], bfhi(p5.x));
    m2[2] = fmaxf(m2[2], bflo(p5.y)); m2[3] = fmaxf(m2[3], bfhi(p5.y));
    m2[4] = fmaxf(m2[4], bflo(p5.z)); m2[5] = fmaxf(m2[5], bfhi(p5.z));
    m2[6] = fmaxf(m2[6], bflo(p5.w)); m2[7] = fmaxf(m2[7], bfhi(p5.w));
    if (da >= -1 && da <= 1) {
      uint4 p3 = *(const uint4*)(rm3 + ro);
      m1[0] = fmaxf(m1[0], bflo(p3.x)); m1[1] = fmaxf(m1[1], bfhi(p3.x));
      m1[2] = fmaxf(m1[2], bflo(p3.y)); m1[3] = fmaxf(m1[3], bfhi(p3.y));
      m1[4] = fmaxf(m1[4], bflo(p3.z)); m1[5] = fmaxf(m1[5], bfhi(p3.z));
      m1[6] = fmaxf(m1[6], bflo(p3.w)); m1[7] = fmaxf(m1[7], bfhi(p3.w));
    }
  }
  float acc[8];
#pragma unroll
  for (int q = 0; q < 8; ++q) acc[q] = 0.f;
#pragma unroll
  for (int dh = 0; dh < 5; ++dh) {
#pragma unroll
    for (int dw = 0; dw < 5; ++dw) {
      float wgt = w5_s[li][dh * 5 + dw];
      uint4 pk = *(const uint4*)(vs + (size_t)(dh * 20 + li + dw) * CH + c0);
      acc[0] = fmaf(wgt, bflo(pk.x), acc[0]);
      acc[1] = fmaf(wgt, bfhi(pk.x), acc[1]);
      acc[2] = fmaf(wgt, bflo(pk.y), acc[2]);
      acc[3] = fmaf(wgt, bfhi(pk.y), acc[3]);
      acc[4] = fmaf(wgt, bflo(pk.z), acc[4]);
      acc[5] = fmaf(wgt, bfhi(pk.z), acc[5]);
      acc[6] = fmaf(wgt, bflo(pk.w), acc[6]);
      acc[7] = fmaf(wgt, bfhi(pk.w), acc[7]);
    }
  }
  unsigned short u1[8], u2[8];
#pragma unroll
  for (int q = 0; q < 8; ++q) {
    float x1v = fmaxf(fmaxf(acc[q], 0.f) + m1[q], 0.f);
    float x2v = fmaxf(x1v + m2[q], 0.f);
    u1[q] = f2bf(x1v);
    u2[q] = f2bf(x2v);
  }
  unsigned short* cp = cat + (size_t)(loc0 + li) * 512 + c0;
  uint4 pk1, pk2;
  pk1.x = u1[0] | ((unsigned)u1[1] << 16); pk1.y = u1[2] | ((unsigned)u1[3] << 16);
  pk1.z = u1[4] | ((unsigned)u1[5] << 16); pk1.w = u1[6] | ((unsigned)u1[7] << 16);
  pk2.x = u2[0] | ((unsigned)u2[1] << 16); pk2.y = u2[2] | ((unsigned)u2[3] << 16);
  pk2.z = u2[4] | ((unsigned)u2[5] << 16); pk2.w = u2[6] | ((unsigned)u2[7] << 16);
  *(uint4*)(cp) = pk1;
  *(uint4*)(cp + 256) = pk2;
}

// ---------------------------------------------------------------------------
// xfu = relu(cat @ Wfu + bfu); outb = bf16(x + xfu) transposed; BN sums (16-banked).
// 128x128 tile, BK=64, K=512, dbuf frag LDS. 512 threads / 8 waves.
__global__ __launch_bounds__(512) void k_fuse(
    const unsigned short* __restrict__ xb, const unsigned short* __restrict__ cat,
    const unsigned short* __restrict__ wfp, const float* __restrict__ bfu,
    unsigned short* __restrict__ outb, float* __restrict__ sums16) {
  __shared__ unsigned short sA[2][16 * 512];
  __shared__ unsigned short sB[2][16 * 512];
  __shared__ float bsum[512];
  int tid = threadIdx.x, lane = tid & 63, w = tid >> 6;
  for (int i = tid; i < 512; i += 512) bsum[i] = 0.f;
  int r0 = (blockIdx.x >> 1) * 128;
  int nc0 = (blockIdx.x & 1) * 128;
  int mh = w >> 1, nq = w & 1;
  floatx4 acc[2][4];
#pragma unroll
  for (int mt = 0; mt < 2; ++mt)
#pragma unroll
    for (int nf = 0; nf < 4; ++nf) acc[mt][nf] = (floatx4)(0.f);
#pragma unroll
  for (int f = 0; f < 4; ++f) {
    int fg = w * 4 + f;
    if (fg < 16) {
      int mt16 = fg >> 1, ks = fg & 1;
      gl_lds16(cat + (size_t)(r0 + mt16 * 16 + (lane & 15)) * 512 + ks * 32 + (lane >> 4) * 8,
               &sA[0][fg * 512]);
    } else {
      int g = fg - 16, nf16 = g >> 1, ks = g & 1;
      gl_lds16(wfp + ((size_t)((nc0 >> 4) + nf16) * 16 + ks) * 512 + lane * 8,
               &sB[0][g * 512]);
    }
  }
  __syncthreads();
  for (int kt = 0; kt < 8; ++kt) {
    int cur = kt & 1;
    if (kt < 7) {
      int kn = kt + 1, nb = kn & 1, kkn = kn * 64;
#pragma unroll
      for (int f = 0; f < 4; ++f) {
        int fg = w * 4 + f;
        if (fg < 16) {
          int mt16 = fg >> 1, ks = fg & 1;
          gl_lds16(cat + (size_t)(r0 + mt16 * 16 + (lane & 15)) * 512 + kkn + ks * 32 + (lane >> 4) * 8,
                   &sA[nb][fg * 512]);
        } else {
          int g = fg - 16, nf16 = g >> 1, ks = g & 1;
          gl_lds16(wfp + ((size_t)((nc0 >> 4) + nf16) * 16 + kn * 2 + ks) * 512 + lane * 8,
                   &sB[nb][g * 512]);
        }
      }
    }
#pragma unroll
    for (int ks = 0; ks < 2; ++ks) {
      short8 af[2], bf[4];
#pragma unroll
      for (int mt = 0; mt < 2; ++mt)
        af[mt] = *(const short8*)&sA[cur][(((mh * 2 + mt) << 1) + ks) * 512 + lane * 8];
#pragma unroll
      for (int nf = 0; nf < 4; ++nf)
        bf[nf] = *(const short8*)&sB[cur][(((nq * 4 + nf) << 1) + ks) * 512 + lane * 8];
#pragma unroll
      for (int mt = 0; mt < 2; ++mt)
#pragma unroll
        for (int nf = 0; nf < 4; ++nf)
          acc[mt][nf] = __builtin_amdgcn_mfma_f32_16x16x32_bf16(af[mt], bf[nf], acc[mt][nf], 0, 0, 0);
    }
    __syncthreads();
  }
#pragma unroll
  for (int nf = 0; nf < 4; ++nf) {
    int c = nc0 + nq * 64 + nf * 16 + (lane & 15);
    float bb = bfu[c];
    float s = 0.f, ss = 0.f;
#pragma unroll
    for (int mt = 0; mt < 2; ++mt) {
      int crow = r0 + mh * 32 + mt * 16 + (lane >> 4) * 4;
#pragma unroll
      for (int i = 0; i < 4; ++i) {
        int r = crow + i;
        float xv = bf2f(xb[(size_t)r * CH + c]);
        float o = xv + fmaxf(acc[mt][nf][i] + bb, 0.f);
        int b_ = r >> 12, al = (r >> 6) & 63, be = r & 63;
        outb[((size_t)(b_ * 64 + be) * 64 + al) * CH + c] = f2bf(o);
        s += o; ss += o * o;
      }
    }
    s += __shfl_xor(s, 16);  s += __shfl_xor(s, 32);
    ss += __shfl_xor(ss, 16); ss += __shfl_xor(ss, 32);
    if (lane < 16) {
      atomicAdd(&bsum[c & 255], s);
      atomicAdd(&bsum[256 + (c & 255)], ss);
    }
  }
  __syncthreads();
  float* bank = sums16 + (size_t)(blockIdx.x & 15) * 512;
  for (int i = tid; i < 512; i += 512) atomicAdd(&bank[i], bsum[i]);
}

// ---------------------------------------------------------------------------
__global__ void k_bnprep(const float* __restrict__ sums16,
                         const float* __restrict__ gamma,
                         const float* __restrict__ beta_,
                         float* __restrict__ sc) {
  int c = threadIdx.x;
  float s = 0.f, ss = 0.f;
#pragma unroll
  for (int bk = 0; bk < 16; ++bk) {
    s += sums16[(size_t)bk * 512 + c];
    ss += sums16[(size_t)bk * 512 + 256 + c];
  }
  const float inv_n = 1.f / (float)NLOC;
  float mean = s * inv_n;
  float var = ss * inv_n - mean * mean;
  float scale = gamma[c] * rsqrtf(var + 1e-5f);
  sc[c] = scale;
  sc[256 + c] = beta_[c] - mean * scale;
}

// ---------------------------------------------------------------------------
__global__ __launch_bounds__(256) void k_bn(
    const unsigned short* __restrict__ outb, float* __restrict__ outp,
    const float* __restrict__ sc, int n8) {
  __shared__ float s[512];
  const int tid = threadIdx.x;
  for (int i = tid; i < 512; i += 256) s[i] = sc[i];
  __syncthreads();
  for (int i = blockIdx.x * 256 + tid; i < n8; i += gridDim.x * 256) {
    uint4 pk = ((const uint4*)outb)[i];
    int c0 = (i & 31) * 8;
    float4 o0, o1;
    o0.x = bflo(pk.x) * s[c0 + 0] + s[256 + c0 + 0];
    o0.y = bfhi(pk.x) * s[c0 + 1] + s[256 + c0 + 1];
    o0.z = bflo(pk.y) * s[c0 + 2] + s[256 + c0 + 2];
    o0.w = bfhi(pk.y) * s[c0 + 3] + s[256 + c0 + 3];
    o1.x = bflo(pk.z) * s[c0 + 4] + s[256 + c0 + 4];
    o1.y = bfhi(pk.z) * s[c0 + 5] + s[256 + c0 + 5];
    o1.z = bflo(pk.w) * s[c0 + 6] + s[256 + c0 + 6];
    o1.w = bfhi(pk.w) * s[c0 + 7] + s[256 + c0 + 7];
    ((float4*)outp)[i * 2] = o0;
    ((float4*)outp)[i * 2 + 1] = o1;
  }
}

// ---------------------------------------------------------------------------
extern "C" void kernel_launch(void* const* d_in, const int* in_sizes, int n_in,
                              void* d_out, int out_size, void* d_ws, size_t ws_size,
                              hipStream_t stream) {
  const float* x     = (const float*)d_in[0];
  const float* Wv    = (const float*)d_in[1];
  const float* bv    = (const float*)d_in[2];
  const float* Wa    = (const float*)d_in[3];
  const float* ba    = (const float*)d_in[4];
  const float* Wfu   = (const float*)d_in[5];
  const float* bfu   = (const float*)d_in[6];
  const float* gamma = (const float*)d_in[7];
  const float* beta_ = (const float*)d_in[8];
  float* out = (float*)d_out;

  float* sums16 = (float*)d_ws;                             // 16*512 f32
  float* sc     = sums16 + 16 * 512;                        // 512 f32
  unsigned short* wp   = (unsigned short*)(sc + 512);       // 432*512 bf16
  unsigned short* wvp  = wp;
  unsigned short* wfp  = wp + (size_t)128 * 512;
  unsigned short* wap  = wp + (size_t)384 * 512;
  unsigned short* vbuf = wp + (size_t)432 * 512;            // NLOC*256 bf16 (v; reused as outb)
  unsigned short* Abuf = vbuf + (size_t)NLOC * CH;          // NLOC*81 bf16
  unsigned short* cat  = Abuf + (size_t)NLOC * 81;          // NLOC*512 bf16
  unsigned short* rm3  = cat + (size_t)NLOC * 512;          // NLOC*256 bf16
  unsigned short* rm5  = rm3 + (size_t)NLOC * CH;           // NLOC*256 bf16
  unsigned short* xb   = rm5 + (size_t)NLOC * CH;           // NLOC*256 bf16
  unsigned short* outb = vbuf;  // v dead after k_attn -> reuse for pre-BN out

  hipMemsetAsync(sums16, 0, 16 * 512 * sizeof(float), stream);

  k_pack_w<<<432, 64, 0, stream>>>(Wv, Wa, Wfu, wp);
  k_pool<<<8192, 256, 0, stream>>>(x, rm3, rm5, xb);
  k_gemm_v<<<512, 512, 0, stream>>>(xb, wvp, bv, vbuf);
  k_gemm_a<<<512, 256, 0, stream>>>(xb, wap, ba, Abuf);
  k_attn<<<2048, 512, 0, stream>>>(Abuf, vbuf, rm3, rm5, cat);
  k_fuse<<<512, 512, 0, stream>>>(xb, cat, wfp, bfu, outb, sums16);
  k_bnprep<<<1, 256, 0, stream>>>(sums16, gamma, beta_, sc);
  k_bn<<<2048, 256, 0, stream>>>(outb, out, sc, NLOC * CH / 8);
}

// Round 23
// 116.044 us; speedup vs baseline: 1.1474x; 1.0132x over previous
//
#include <hip/hip_runtime.h>
#include <math.h>

#define NLOC 32768
#define CH 256

typedef __attribute__((ext_vector_type(8))) short short8;
typedef __attribute__((ext_vector_type(4))) float floatx4;

__device__ inline unsigned short f2bf(float x) {
  union { float f; unsigned u; } c; c.f = x;
  unsigned r = c.u + 0x7FFFu + ((c.u >> 16) & 1u);
  return (unsigned short)(r >> 16);
}
__device__ inline float bflo(unsigned u) {
  union { unsigned u; float f; } c; c.u = u << 16; return c.f;
}
__device__ inline float bfhi(unsigned u) {
  union { unsigned u; float f; } c; c.u = u & 0xFFFF0000u; return c.f;
}
__device__ inline float bf2f(unsigned short u) {
  union { unsigned u; float f; } c; c.u = (unsigned)u << 16; return c.f;
}

// async global->LDS 16B: lds dest is wave-uniform base (+lane*16 by HW)
__device__ __forceinline__ void gl_lds16(const void* g, void* l) {
  __builtin_amdgcn_global_load_lds(
      (const __attribute__((address_space(1))) unsigned int*)g,
      (__attribute__((address_space(3))) unsigned int*)l, 16, 0, 0);
}

// ---------------------------------------------------------------------------
// P0: pack Wv/Wfu/Wa(->96 cols, zero-pad) to bf16 MFMA B-fragment order.
__global__ __launch_bounds__(64) void k_pack_w(
    const float* __restrict__ Wv, const float* __restrict__ Wa,
    const float* __restrict__ Wfu, unsigned short* __restrict__ wp) {
  int fid = blockIdx.x;
  int l = threadIdx.x;
  const float* W; int ldn, nvalid, nf, ks;
  if (fid < 128)      { W = Wv;  ldn = 256; nvalid = 256; nf = fid >> 3; ks = fid & 7; }
  else if (fid < 384) { int f = fid - 128; W = Wfu; ldn = 256; nvalid = 256; nf = f >> 4; ks = f & 15; }
  else                { int f = fid - 384; W = Wa;  ldn = 81;  nvalid = 81;  nf = f >> 3; ks = f & 7; }
  unsigned short* dst = wp + (size_t)fid * 512;
  int c = nf * 16 + (l & 15);
  int k0 = ks * 32 + (l >> 4) * 8;
  unsigned short u[8];
#pragma unroll
  for (int j = 0; j < 8; ++j)
    u[j] = (c < nvalid) ? f2bf(W[(size_t)(k0 + j) * ldn + c]) : (unsigned short)0;
  uint4 pk;
  pk.x = u[0] | ((unsigned)u[1] << 16);
  pk.y = u[2] | ((unsigned)u[3] << 16);
  pk.z = u[4] | ((unsigned)u[5] << 16);
  pk.w = u[6] | ((unsigned)u[7] << 16);
  *(uint4*)(dst + l * 8) = pk;
}

// ---------------------------------------------------------------------------
// Separable maxpool row-pass along beta + bf16 cast of x. One thread per (loc,c4)
__global__ __launch_bounds__(256) void k_pool(
    const float* __restrict__ x, unsigned short* __restrict__ rm3,
    unsigned short* __restrict__ rm5, unsigned short* __restrict__ xb) {
  int tid = threadIdx.x;
  int loc = blockIdx.x * 4 + (tid >> 6);
  int beta = loc & 63;
  int c0 = (tid & 63) * 4;
  const float* base = x + ((size_t)loc - beta) * CH + c0;
  const float NI = -INFINITY;
  float4 r3 = {NI, NI, NI, NI}, r5, xv;
#pragma unroll
  for (int d = -1; d <= 1; ++d) {
    int bb = beta + d;
    if ((unsigned)bb >= 64u) continue;
    float4 f = *(const float4*)(base + (size_t)bb * CH);
    if (d == 0) xv = f;
    r3.x = fmaxf(r3.x, f.x); r3.y = fmaxf(r3.y, f.y);
    r3.z = fmaxf(r3.z, f.z); r3.w = fmaxf(r3.w, f.w);
  }
  r5 = r3;
#pragma unroll
  for (int d = -2; d <= 2; d += 4) {
    int bb = beta + d;
    if ((unsigned)bb >= 64u) continue;
    float4 f = *(const float4*)(base + (size_t)bb * CH);
    r5.x = fmaxf(r5.x, f.x); r5.y = fmaxf(r5.y, f.y);
    r5.z = fmaxf(r5.z, f.z); r5.w = fmaxf(r5.w, f.w);
  }
  size_t o = (size_t)loc * CH + c0;
  uint2 p3, p5, px;
  p3.x = f2bf(r3.x) | ((unsigned)f2bf(r3.y) << 16);
  p3.y = f2bf(r3.z) | ((unsigned)f2bf(r3.w) << 16);
  p5.x = f2bf(r5.x) | ((unsigned)f2bf(r5.y) << 16);
  p5.y = f2bf(r5.z) | ((unsigned)f2bf(r5.w) << 16);
  px.x = f2bf(xv.x) | ((unsigned)f2bf(xv.y) << 16);
  px.y = f2bf(xv.z) | ((unsigned)f2bf(xv.w) << 16);
  *(uint2*)(rm3 + o) = p3;
  *(uint2*)(rm5 + o) = p5;
  *(uint2*)(xb + o) = px;
}

// ---------------------------------------------------------------------------
// v = xb @ Wv + bv -> bf16 [loc][256]. 128x128 tile, BK=64, dbuf frag LDS.
// 512 threads / 8 waves.
__global__ __launch_bounds__(512) void k_gemm_v(
    const unsigned short* __restrict__ xb, const unsigned short* __restrict__ wvp,
    const float* __restrict__ bv, unsigned short* __restrict__ v) {
  __shared__ unsigned short sA[2][16 * 512];
  __shared__ unsigned short sB[2][16 * 512];
  int tid = threadIdx.x, lane = tid & 63, w = tid >> 6;
  int r0 = (blockIdx.x >> 1) * 128;
  int nc0 = (blockIdx.x & 1) * 128;
  int mh = w >> 1, nq = w & 1;
  floatx4 acc[2][4];
#pragma unroll
  for (int mt = 0; mt < 2; ++mt)
#pragma unroll
    for (int nf = 0; nf < 4; ++nf) acc[mt][nf] = (floatx4)(0.f);
#pragma unroll
  for (int f = 0; f < 4; ++f) {
    int fg = w * 4 + f;
    if (fg < 16) {
      int mt16 = fg >> 1, ks = fg & 1;
      gl_lds16(xb + (size_t)(r0 + mt16 * 16 + (lane & 15)) * CH + ks * 32 + (lane >> 4) * 8,
               &sA[0][fg * 512]);
    } else {
      int g = fg - 16, nf16 = g >> 1, ks = g & 1;
      gl_lds16(wvp + ((size_t)((nc0 >> 4) + nf16) * 8 + ks) * 512 + lane * 8,
               &sB[0][g * 512]);
    }
  }
  __syncthreads();
  for (int kt = 0; kt < 4; ++kt) {
    int cur = kt & 1;
    if (kt < 3) {
      int kn = kt + 1, nb = kn & 1, kkn = kn * 64;
#pragma unroll
      for (int f = 0; f < 4; ++f) {
        int fg = w * 4 + f;
        if (fg < 16) {
          int mt16 = fg >> 1, ks = fg & 1;
          gl_lds16(xb + (size_t)(r0 + mt16 * 16 + (lane & 15)) * CH + kkn + ks * 32 + (lane >> 4) * 8,
                   &sA[nb][fg * 512]);
        } else {
          int g = fg - 16, nf16 = g >> 1, ks = g & 1;
          gl_lds16(wvp + ((size_t)((nc0 >> 4) + nf16) * 8 + kn * 2 + ks) * 512 + lane * 8,
                   &sB[nb][g * 512]);
        }
      }
    }
#pragma unroll
    for (int ks = 0; ks < 2; ++ks) {
      short8 af[2], bf[4];
#pragma unroll
      for (int mt = 0; mt < 2; ++mt)
        af[mt] = *(const short8*)&sA[cur][(((mh * 2 + mt) << 1) + ks) * 512 + lane * 8];
#pragma unroll
      for (int nf = 0; nf < 4; ++nf)
        bf[nf] = *(const short8*)&sB[cur][(((nq * 4 + nf) << 1) + ks) * 512 + lane * 8];
#pragma unroll
      for (int mt = 0; mt < 2; ++mt)
#pragma unroll
        for (int nf = 0; nf < 4; ++nf)
          acc[mt][nf] = __builtin_amdgcn_mfma_f32_16x16x32_bf16(af[mt], bf[nf], acc[mt][nf], 0, 0, 0);
    }
    __syncthreads();
  }
#pragma unroll
  for (int nf = 0; nf < 4; ++nf) {
    int c = nc0 + nq * 64 + nf * 16 + (lane & 15);
    float bb = bv[c];
#pragma unroll
    for (int mt = 0; mt < 2; ++mt) {
      int crow = r0 + mh * 32 + mt * 16 + (lane >> 4) * 4;
#pragma unroll
      for (int i = 0; i < 4; ++i)
        v[(size_t)(crow + i) * CH + c] = f2bf(acc[mt][nf][i] + bb);
    }
  }
}

// ---------------------------------------------------------------------------
// logits = xb @ Wa + ba (96 cols, 81 valid) -> softmax9 -> A bf16 [loc][81]
__global__ __launch_bounds__(256) void k_gemm_a(
    const unsigned short* __restrict__ xb, const unsigned short* __restrict__ wap,
    const float* __restrict__ ba, unsigned short* __restrict__ A) {
  __shared__ float lg[64][96];
  int tid = threadIdx.x, lane = tid & 63, w = tid >> 6;
  int mtile = blockIdx.x * 4 + w;
  int r0 = mtile * 16;
  floatx4 acc[6];
#pragma unroll
  for (int i = 0; i < 6; ++i) acc[i] = (floatx4)(0.f);
  const unsigned short* abase = xb + (size_t)(r0 + (lane & 15)) * CH + (lane >> 4) * 8;
  for (int ks = 0; ks < 8; ++ks) {
    short8 af = *(const short8*)(abase + ks * 32);
#pragma unroll
    for (int nf = 0; nf < 6; ++nf) {
      short8 bfr = *(const short8*)(wap + ((size_t)(nf * 8) + ks) * 512 + lane * 8);
      acc[nf] = __builtin_amdgcn_mfma_f32_16x16x32_bf16(af, bfr, acc[nf], 0, 0, 0);
    }
  }
  int lrow = w * 16 + (lane >> 4) * 4;
#pragma unroll
  for (int nf = 0; nf < 6; ++nf) {
    int c = nf * 16 + (lane & 15);
    float bb = (c < 81) ? ba[c] : 0.f;
#pragma unroll
    for (int i = 0; i < 4; ++i)
      lg[lrow + i][c] = acc[nf][i] + bb;
  }
  __syncthreads();
  int loc0 = blockIdx.x * 64;
  for (int it = 0; it < 3; ++it) {
    int idx = tid + it * 256;
    if (idx < 576) {
      int row = idx / 9, g = idx % 9;
      float vals[9];
#pragma unroll
      for (int q = 0; q < 9; ++q) vals[q] = lg[row][g * 9 + q];
      float m = vals[0];
#pragma unroll
      for (int q = 1; q < 9; ++q) m = fmaxf(m, vals[q]);
      float s = 0.f;
#pragma unroll
      for (int q = 0; q < 9; ++q) { vals[q] = __expf(vals[q] - m); s += vals[q]; }
      float inv = 1.f / s;
      unsigned short* o = A + (size_t)(loc0 + row) * 81 + g * 9;
#pragma unroll
      for (int q = 0; q < 9; ++q) o[q] = f2bf(vals[q] * inv);
    }
  }
}

// ---------------------------------------------------------------------------
// attention gather + col-max of rm3/rm5 -> cat [loc][512] bf16
// 16-beta blocks: 512 threads = 16 betas x 32 ch-threads (8 ch each).
// bf16 LDS window [5][20][256] = 51.2KB; a_s overlays head. XCD swizzle (2048).
__global__ __launch_bounds__(512) void k_attn(
    const unsigned short* __restrict__ A, const unsigned short* __restrict__ v,
    const unsigned short* __restrict__ rm3, const unsigned short* __restrict__ rm5,
    unsigned short* __restrict__ cat) {
  __shared__ unsigned short vs[5 * 20 * CH];   // 51200 B; head doubles as a_s
  __shared__ float w5_s[16][25];               // 1600 B
  float* a_sf = (float*)vs;                    // [16][81] f32 = 5184 B (dead after fold)
  int tid = threadIdx.x;
  int bid = (blockIdx.x & 7) * 256 + (blockIdx.x >> 3);
  int loc0 = bid * 16;
  int b = loc0 >> 12, alpha = (loc0 >> 6) & 63, beta0 = loc0 & 63;
  for (int idx = tid; idx < 16 * 81; idx += 512) {
    int li = idx / 81, t = idx - li * 81;
    int ij = t / 9, i = ij / 3, j = ij % 3;
    int lh = beta0 + li + 1 - i;
    int lw = alpha + 1 - j;
    float val = 0.f;
    if ((unsigned)lh < 64u && (unsigned)lw < 64u)
      val = bf2f(A[(size_t)(b * 4096 + lh * 64 + lw) * 81 + t]);
    a_sf[li * 81 + t] = val;
  }
  __syncthreads();
  if (tid < 400) {
    int li = tid / 25, o = tid - li * 25;
    int dh = o / 5 - 2, dw = o % 5 - 2;
    float s = 0.f;
    int jlo = dh < 0 ? -dh : 0, jhi = dh > 0 ? 2 - dh : 2;
    int ilo = dw < 0 ? -dw : 0, ihi = dw > 0 ? 2 - dw : 2;
    for (int j = jlo; j <= jhi; ++j)
      for (int i = ilo; i <= ihi; ++i)
        s += a_sf[li * 81 + (i * 3 + j) * 9 + ((i + dw) * 3 + (j + dh))];
    w5_s[li][o] = s;
  }
  __syncthreads();   // a_s dead
  const unsigned short* vb = v + (size_t)b * 4096 * CH;
  for (int i = tid; i < 3200; i += 512) {
    int row = i / 640, rem = i - row * 640, col = rem >> 5, ch8 = rem & 31;
    int hv = alpha - 2 + row, wv = beta0 - 2 + col;
    uint4 val = {0u, 0u, 0u, 0u};
    if ((unsigned)hv < 64u && (unsigned)wv < 64u)
      val = *(const uint4*)(vb + (size_t)(hv * 64 + wv) * CH + ch8 * 8);
    *(uint4*)(vs + (size_t)(row * 20 + col) * CH + ch8 * 8) = val;
  }
  __syncthreads();
  int li = tid >> 5, tc = tid & 31, c0 = tc * 8;
  int beta = beta0 + li;
  float m1[8], m2[8];
#pragma unroll
  for (int q = 0; q < 8; ++q) { m1[q] = -INFINITY; m2[q] = -INFINITY; }
#pragma unroll
  for (int da = -2; da <= 2; ++da) {
    int aa = alpha + da;
    if ((unsigned)aa >= 64u) continue;
    size_t ro = (size_t)((b * 64 + aa) * 64 + beta) * CH + c0;
    uint4 p5 = *(const uint4*)(rm5 + ro);
    m2[0] = fmaxf(m2[0], bflo(p5.x)); m2[1] = fmaxf(m2[1], bfhi(p5.x));
    m2[2] = fmaxf(m2[2], bflo(p5.y)); m2[3] = fmaxf(m2[3], bfhi(p5.y));
    m2[4] = fmaxf(m2[4], bflo(p5.z)); m2[5] = fmaxf(m2[5], bfhi(p5.z));
    m2[6] = fmaxf(m2[6], bflo(p5.w)); m2[7] = fmaxf(m2[7], bfhi(p5.w));
    if (da >= -1 && da <= 1) {
      uint4 p3 = *(const uint4*)(rm3 + ro);
      m1[0] = fmaxf(m1[0], bflo(p3.x)); m1[1] = fmaxf(m1[1], bfhi(p3.x));
      m1[2] = fmaxf(m1[2], bflo(p3.y)); m1[3] = fmaxf(m1[3], bfhi(p3.y));
      m1[4] = fmaxf(m1[4], bflo(p3.z)); m1[5] = fmaxf(m1[5], bfhi(p3.z));
      m1[6] = fmaxf(m1[6], bflo(p3.w)); m1[7] = fmaxf(m1[7], bfhi(p3.w));
    }
  }
  float acc[8];
#pragma unroll
  for (int q = 0; q < 8; ++q) acc[q] = 0.f;
#pragma unroll
  for (int dh = 0; dh < 5; ++dh) {
#pragma unroll
    for (int dw = 0; dw < 5; ++dw) {
      float wgt = w5_s[li][dh * 5 + dw];
      uint4 pk = *(const uint4*)(vs + (size_t)(dh * 20 + li + dw) * CH + c0);
      acc[0] = fmaf(wgt, bflo(pk.x), acc[0]);
      acc[1] = fmaf(wgt, bfhi(pk.x), acc[1]);
      acc[2] = fmaf(wgt, bflo(pk.y), acc[2]);
      acc[3] = fmaf(wgt, bfhi(pk.y), acc[3]);
      acc[4] = fmaf(wgt, bflo(pk.z), acc[4]);
      acc[5] = fmaf(wgt, bfhi(pk.z), acc[5]);
      acc[6] = fmaf(wgt, bflo(pk.w), acc[6]);
      acc[7] = fmaf(wgt, bfhi(pk.w), acc[7]);
    }
  }
  unsigned short u1[8], u2[8];
#pragma unroll
  for (int q = 0; q < 8; ++q) {
    float x1v = fmaxf(fmaxf(acc[q], 0.f) + m1[q], 0.f);
    float x2v = fmaxf(x1v + m2[q], 0.f);
    u1[q] = f2bf(x1v);
    u2[q] = f2bf(x2v);
  }
  unsigned short* cp = cat + (size_t)(loc0 + li) * 512 + c0;
  uint4 pk1, pk2;
  pk1.x = u1[0] | ((unsigned)u1[1] << 16); pk1.y = u1[2] | ((unsigned)u1[3] << 16);
  pk1.z = u1[4] | ((unsigned)u1[5] << 16); pk1.w = u1[6] | ((unsigned)u1[7] << 16);
  pk2.x = u2[0] | ((unsigned)u2[1] << 16); pk2.y = u2[2] | ((unsigned)u2[3] << 16);
  pk2.z = u2[4] | ((unsigned)u2[5] << 16); pk2.w = u2[6] | ((unsigned)u2[7] << 16);
  *(uint4*)(cp) = pk1;
  *(uint4*)(cp + 256) = pk2;
}

// ---------------------------------------------------------------------------
// xfu = relu(cat @ Wfu + bfu); outb = bf16(x + xfu) transposed; BN sums (16-banked).
// 128x128 tile, BK=64, K=512, dbuf frag LDS. 512 threads / 8 waves.
__global__ __launch_bounds__(512) void k_fuse(
    const unsigned short* __restrict__ xb, const unsigned short* __restrict__ cat,
    const unsigned short* __restrict__ wfp, const float* __restrict__ bfu,
    unsigned short* __restrict__ outb, float* __restrict__ sums16) {
  __shared__ unsigned short sA[2][16 * 512];
  __shared__ unsigned short sB[2][16 * 512];
  __shared__ float bsum[512];
  int tid = threadIdx.x, lane = tid & 63, w = tid >> 6;
  for (int i = tid; i < 512; i += 512) bsum[i] = 0.f;
  int r0 = (blockIdx.x >> 1) * 128;
  int nc0 = (blockIdx.x & 1) * 128;
  int mh = w >> 1, nq = w & 1;
  floatx4 acc[2][4];
#pragma unroll
  for (int mt = 0; mt < 2; ++mt)
#pragma unroll
    for (int nf = 0; nf < 4; ++nf) acc[mt][nf] = (floatx4)(0.f);
#pragma unroll
  for (int f = 0; f < 4; ++f) {
    int fg = w * 4 + f;
    if (fg < 16) {
      int mt16 = fg >> 1, ks = fg & 1;
      gl_lds16(cat + (size_t)(r0 + mt16 * 16 + (lane & 15)) * 512 + ks * 32 + (lane >> 4) * 8,
               &sA[0][fg * 512]);
    } else {
      int g = fg - 16, nf16 = g >> 1, ks = g & 1;
      gl_lds16(wfp + ((size_t)((nc0 >> 4) + nf16) * 16 + ks) * 512 + lane * 8,
               &sB[0][g * 512]);
    }
  }
  __syncthreads();
  for (int kt = 0; kt < 8; ++kt) {
    int cur = kt & 1;
    if (kt < 7) {
      int kn = kt + 1, nb = kn & 1, kkn = kn * 64;
#pragma unroll
      for (int f = 0; f < 4; ++f) {
        int fg = w * 4 + f;
        if (fg < 16) {
          int mt16 = fg >> 1, ks = fg & 1;
          gl_lds16(cat + (size_t)(r0 + mt16 * 16 + (lane & 15)) * 512 + kkn + ks * 32 + (lane >> 4) * 8,
                   &sA[nb][fg * 512]);
        } else {
          int g = fg - 16, nf16 = g >> 1, ks = g & 1;
          gl_lds16(wfp + ((size_t)((nc0 >> 4) + nf16) * 16 + kn * 2 + ks) * 512 + lane * 8,
                   &sB[nb][g * 512]);
        }
      }
    }
#pragma unroll
    for (int ks = 0; ks < 2; ++ks) {
      short8 af[2], bf[4];
#pragma unroll
      for (int mt = 0; mt < 2; ++mt)
        af[mt] = *(const short8*)&sA[cur][(((mh * 2 + mt) << 1) + ks) * 512 + lane * 8];
#pragma unroll
      for (int nf = 0; nf < 4; ++nf)
        bf[nf] = *(const short8*)&sB[cur][(((nq * 4 + nf) << 1) + ks) * 512 + lane * 8];
#pragma unroll
      for (int mt = 0; mt < 2; ++mt)
#pragma unroll
        for (int nf = 0; nf < 4; ++nf)
          acc[mt][nf] = __builtin_amdgcn_mfma_f32_16x16x32_bf16(af[mt], bf[nf], acc[mt][nf], 0, 0, 0);
    }
    __syncthreads();
  }
#pragma unroll
  for (int nf = 0; nf < 4; ++nf) {
    int c = nc0 + nq * 64 + nf * 16 + (lane & 15);
    float bb = bfu[c];
    float s = 0.f, ss = 0.f;
#pragma unroll
    for (int mt = 0; mt < 2; ++mt) {
      int crow = r0 + mh * 32 + mt * 16 + (lane >> 4) * 4;
#pragma unroll
      for (int i = 0; i < 4; ++i) {
        int r = crow + i;
        float xv = bf2f(xb[(size_t)r * CH + c]);
        float o = xv + fmaxf(acc[mt][nf][i] + bb, 0.f);
        int b_ = r >> 12, al = (r >> 6) & 63, be = r & 63;
        outb[((size_t)(b_ * 64 + be) * 64 + al) * CH + c] = f2bf(o);
        s += o; ss += o * o;
      }
    }
    s += __shfl_xor(s, 16);  s += __shfl_xor(s, 32);
    ss += __shfl_xor(ss, 16); ss += __shfl_xor(ss, 32);
    if (lane < 16) {
      atomicAdd(&bsum[c & 255], s);
      atomicAdd(&bsum[256 + (c & 255)], ss);
    }
  }
  __syncthreads();
  float* bank = sums16 + (size_t)(blockIdx.x & 15) * 512;
  for (int i = tid; i < 512; i += 512) atomicAdd(&bank[i], bsum[i]);
}

// ---------------------------------------------------------------------------
// k_bn: fused BN-prep (each block reduces sums16 redundantly) + normalize.
__global__ __launch_bounds__(256) void k_bn(
    const unsigned short* __restrict__ outb, float* __restrict__ outp,
    const float* __restrict__ sums16, const float* __restrict__ gamma,
    const float* __restrict__ beta_, int n8) {
  __shared__ float s[512];
  const int tid = threadIdx.x;
  {
    int c = tid;   // 256 threads -> 256 channels
    float sum = 0.f, ssum = 0.f;
#pragma unroll
    for (int bk = 0; bk < 16; ++bk) {
      sum  += sums16[(size_t)bk * 512 + c];
      ssum += sums16[(size_t)bk * 512 + 256 + c];
    }
    const float inv_n = 1.f / (float)NLOC;
    float mean = sum * inv_n;
    float var = ssum * inv_n - mean * mean;
    float scale = gamma[c] * rsqrtf(var + 1e-5f);
    s[c] = scale;
    s[256 + c] = beta_[c] - mean * scale;
  }
  __syncthreads();
  for (int i = blockIdx.x * 256 + tid; i < n8; i += gridDim.x * 256) {
    uint4 pk = ((const uint4*)outb)[i];
    int c0 = (i & 31) * 8;
    float4 o0, o1;
    o0.x = bflo(pk.x) * s[c0 + 0] + s[256 + c0 + 0];
    o0.y = bfhi(pk.x) * s[c0 + 1] + s[256 + c0 + 1];
    o0.z = bflo(pk.y) * s[c0 + 2] + s[256 + c0 + 2];
    o0.w = bfhi(pk.y) * s[c0 + 3] + s[256 + c0 + 3];
    o1.x = bflo(pk.z) * s[c0 + 4] + s[256 + c0 + 4];
    o1.y = bfhi(pk.z) * s[c0 + 5] + s[256 + c0 + 5];
    o1.z = bflo(pk.w) * s[c0 + 6] + s[256 + c0 + 6];
    o1.w = bfhi(pk.w) * s[c0 + 7] + s[256 + c0 + 7];
    ((float4*)outp)[i * 2] = o0;
    ((float4*)outp)[i * 2 + 1] = o1;
  }
}

// ---------------------------------------------------------------------------
extern "C" void kernel_launch(void* const* d_in, const int* in_sizes, int n_in,
                              void* d_out, int out_size, void* d_ws, size_t ws_size,
                              hipStream_t stream) {
  const float* x     = (const float*)d_in[0];
  const float* Wv    = (const float*)d_in[1];
  const float* bv    = (const float*)d_in[2];
  const float* Wa    = (const float*)d_in[3];
  const float* ba    = (const float*)d_in[4];
  const float* Wfu   = (const float*)d_in[5];
  const float* bfu   = (const float*)d_in[6];
  const float* gamma = (const float*)d_in[7];
  const float* beta_ = (const float*)d_in[8];
  float* out = (float*)d_out;

  float* sums16 = (float*)d_ws;                             // 16*512 f32
  float* sc     = sums16 + 16 * 512;                        // 512 f32 (unused now)
  unsigned short* wp   = (unsigned short*)(sc + 512);       // 432*512 bf16
  unsigned short* wvp  = wp;
  unsigned short* wfp  = wp + (size_t)128 * 512;
  unsigned short* wap  = wp + (size_t)384 * 512;
  unsigned short* vbuf = wp + (size_t)432 * 512;            // NLOC*256 bf16 (v; reused as outb)
  unsigned short* Abuf = vbuf + (size_t)NLOC * CH;          // NLOC*81 bf16
  unsigned short* cat  = Abuf + (size_t)NLOC * 81;          // NLOC*512 bf16
  unsigned short* rm3  = cat + (size_t)NLOC * 512;          // NLOC*256 bf16
  unsigned short* rm5  = rm3 + (size_t)NLOC * CH;           // NLOC*256 bf16
  unsigned short* xb   = rm5 + (size_t)NLOC * CH;           // NLOC*256 bf16
  unsigned short* outb = vbuf;  // v dead after k_attn -> reuse for pre-BN out

  hipMemsetAsync(sums16, 0, 16 * 512 * sizeof(float), stream);

  k_pack_w<<<432, 64, 0, stream>>>(Wv, Wa, Wfu, wp);
  k_pool<<<8192, 256, 0, stream>>>(x, rm3, rm5, xb);
  k_gemm_v<<<512, 512, 0, stream>>>(xb, wvp, bv, vbuf);
  k_gemm_a<<<512, 256, 0, stream>>>(xb, wap, ba, Abuf);
  k_attn<<<2048, 512, 0, stream>>>(Abuf, vbuf, rm3, rm5, cat);
  k_fuse<<<512, 512, 0, stream>>>(xb, cat, wfp, bfu, outb, sums16);
  k_bn<<<2048, 256, 0, stream>>>(outb, out, sums16, gamma, beta_, NLOC * CH / 8);
}